// Round 1
// 670.909 us; speedup vs baseline: 1.0529x; 1.0529x over previous
//
#include <hip/hip_runtime.h>

typedef unsigned short u16;
typedef __bf16 bf16x8 __attribute__((ext_vector_type(8)));
typedef float f4 __attribute__((ext_vector_type(4)));
typedef float float4v __attribute__((ext_vector_type(4)));
typedef u16 u16x4 __attribute__((ext_vector_type(4)));

#define NX 11796480   // B*T*D = 3840*3072
#define LDP 136       // padded LDS row (u16 elems) for P / Vt in temporal attn

__device__ __forceinline__ float bf2f(u16 u){ __bf16 h = __builtin_bit_cast(__bf16, u); return (float)h; }
__device__ __forceinline__ u16 f2bf(float f){ __bf16 h = (__bf16)f; return __builtin_bit_cast(u16, h); }

__device__ __forceinline__ void gload_lds16(const u16* g, u16* l){
  __builtin_amdgcn_global_load_lds((const __attribute__((address_space(1))) void*)g,
                                   (__attribute__((address_space(3))) void*)l, 16, 0, 0);
}

// ---------------- fused prep: zero BN accs + all fp32->bf16 conversions + QKV weight pack ----------------
__device__ __forceinline__ void cvt4seg(const float* __restrict__ in, u16* __restrict__ out, int i){
  float4v v = *(const float4v*)&in[i*4];
  u16x4 o;
  o[0]=f2bf(v[0]); o[1]=f2bf(v[1]); o[2]=f2bf(v[2]); o[3]=f2bf(v[3]);
  *(u16x4*)&out[i*4] = o;
}

// total items = 18432 + 2949120 + 2359296 + 2359296 + 196608 + 196608 + 2359296 = 10438656 = 40776*256
__global__ void k_prep(const float* __restrict__ src, u16* __restrict__ x_bf,
                       const float* __restrict__ wpt, u16* __restrict__ wptb,
                       const float* __restrict__ wps, u16* __restrict__ wpsb,
                       const float* __restrict__ w1,  u16* __restrict__ w1b,
                       const float* __restrict__ w2,  u16* __restrict__ w2b,
                       const float* __restrict__ wqt, const float* __restrict__ wkt,
                       const float* __restrict__ wvt, const float* __restrict__ wqs,
                       const float* __restrict__ wks, const float* __restrict__ wvs,
                       u16* __restrict__ wcat, float* __restrict__ accs){
  int i = blockIdx.x*256 + threadIdx.x;
  if (i < 18432){ accs[i] = 0.f; return; }
  i -= 18432;
  if (i < 2949120){ cvt4seg(src, x_bf, i); return; }
  i -= 2949120;
  if (i < 2359296){ cvt4seg(wpt, wptb, i); return; }
  i -= 2359296;
  if (i < 2359296){ cvt4seg(wps, wpsb, i); return; }
  i -= 2359296;
  if (i < 196608){ cvt4seg(w1, w1b, i); return; }
  i -= 196608;
  if (i < 196608){ cvt4seg(w2, w2b, i); return; }
  i -= 196608;
  // pack Wq_t|Wk_t|Wv_t|Wq_s|Wk_s|Wv_s into (J=24, N=768, K=128) row-major bf16
  int e = i & 127;
  int n = (i >> 7) % 768;
  int j = i / (768*128);
  float v;
  if (n < 512){
    int tn = n >> 7, hh = (n >> 4) & 7, dd = n & 15;
    const float* W = (tn==0)? wqt : (tn==1)? wkt : (tn==2)? wvt : wqs;  // (H,J,d,E)
    v = W[(((hh*24 + j)*16 + dd) << 7) + e];
  } else {
    int m = n - 512;
    int tn = m >> 7, hh = (m >> 4) & 7, dd = m & 15;
    const float* W = (tn==0)? wks : wvs;                                // (H,d,E)
    v = W[((hh*16 + dd) << 7) + e];
  }
  wcat[i] = f2bf(v);
}

// ---------------- MFMA GEMM core (BK=64): C[128,128] tile of A[M,K]*B[N,K]^T ----------------
// (kept for gemm_relu / gemm_ff2 — small-K GEMMs)
__device__ __forceinline__ void gemm_tile(const u16* __restrict__ Ab, int lda,
                                          const u16* __restrict__ Bb, int ldb,
                                          int K, f4 acc[4][4], u16* As, u16* Bs)
{
  const int tid  = threadIdx.x;
  const int lane = tid & 63;
  const int wid  = tid >> 6;
  const int waveM = (wid >> 1) * 64;
  const int waveN = (wid & 1) * 64;
  const int quad = lane >> 4;
  const int r16  = lane & 15;
  const int srow = tid >> 3;                       // 0..31
  const int gcol = ((tid & 7) ^ (srow & 7)) * 8;   // swizzled source column

  #pragma unroll
  for (int mt=0; mt<4; mt++)
    #pragma unroll
    for (int nt=0; nt<4; nt++)
      #pragma unroll
      for (int q=0; q<4; q++) acc[mt][nt][q] = 0.f;

  for (int k0 = 0; k0 < K; k0 += 64){
    __syncthreads();
    #pragma unroll
    for (int i=0; i<4; i++){
      int row = srow + i*32;
      gload_lds16(&Ab[(size_t)row*lda + k0 + gcol], As + wid*512 + i*2048);
      gload_lds16(&Bb[(size_t)row*ldb + k0 + gcol], Bs + wid*512 + i*2048);
    }
    __builtin_amdgcn_s_waitcnt(0);
    __syncthreads();
    #pragma unroll
    for (int kk=0; kk<2; kk++){
      bf16x8 af[4], bfr[4];
      const int soff = ((kk*4 + quad) ^ (r16 & 7)) * 8;   // swizzled read slot
      #pragma unroll
      for (int mt=0; mt<4; mt++)
        af[mt] = *(const bf16x8*)&As[(waveM + mt*16 + r16)*64 + soff];
      #pragma unroll
      for (int nt=0; nt<4; nt++)
        bfr[nt] = *(const bf16x8*)&Bs[(waveN + nt*16 + r16)*64 + soff];
      #pragma unroll
      for (int mt=0; mt<4; mt++)
        #pragma unroll
        for (int nt=0; nt<4; nt++)
          acc[mt][nt] = __builtin_amdgcn_mfma_f32_16x16x32_bf16(af[mt], bfr[nt], acc[mt][nt], 0, 0, 0);
    }
  }
  __syncthreads();
}

// ---------------- QKV GEMM: stage A once, loop 6 B-chunks of 128 (N=768 total) ----------------
__global__ __launch_bounds__(256)
void gemm_qkv(const u16* __restrict__ x, const u16* __restrict__ wcat,
              u16* __restrict__ qt, u16* __restrict__ kt, u16* __restrict__ vt,
              u16* __restrict__ qs, u16* __restrict__ ks, u16* __restrict__ vs)
{
  __shared__ __align__(16) u16 As[128*128];
  __shared__ __align__(16) u16 Bs[128*128];
  int m0 = blockIdx.x*128, j = blockIdx.y;
  const u16* Ab = x + (size_t)m0*3072 + j*128;
  const u16* Bbase = wcat + (size_t)j*98304;
  int tid = threadIdx.x, lane = tid & 63, wid = tid >> 6;
  int quad = lane >> 4, r16 = lane & 15;
  int srow16 = tid >> 4;                   // 0..15
  int cslot  = tid & 15;
  int gcol   = (cslot ^ srow16) * 8;       // swizzled source column

  #pragma unroll
  for (int it=0; it<8; it++){
    int row = srow16 + it*16;
    gload_lds16(&Ab[(size_t)row*3072 + gcol], As + tid*8 + it*2048);
  }

  int waveM = (wid>>1)*64, waveN = (wid&1)*64;

  for (int nc=0; nc<6; nc++){
    const u16* Bb = Bbase + (size_t)(nc*128)*128;
    #pragma unroll
    for (int it=0; it<8; it++){
      int row = srow16 + it*16;
      gload_lds16(&Bb[(size_t)row*128 + gcol], Bs + tid*8 + it*2048);
    }
    __builtin_amdgcn_s_waitcnt(0);
    __syncthreads();

    f4 acc[4][4];
    #pragma unroll
    for (int mt=0; mt<4; mt++)
      #pragma unroll
      for (int nt=0; nt<4; nt++)
        #pragma unroll
        for (int q=0; q<4; q++) acc[mt][nt][q] = 0.f;

    #pragma unroll
    for (int kk=0; kk<4; kk++){
      bf16x8 af[4], bfr[4];
      const int soff = ((kk*4 + quad) ^ r16) * 8;
      #pragma unroll
      for (int mt=0; mt<4; mt++)
        af[mt] = *(const bf16x8*)&As[(waveM + mt*16 + r16)*128 + soff];
      #pragma unroll
      for (int nt=0; nt<4; nt++)
        bfr[nt] = *(const bf16x8*)&Bs[(waveN + nt*16 + r16)*128 + soff];
      #pragma unroll
      for (int mt=0; mt<4; mt++)
        #pragma unroll
        for (int nt=0; nt<4; nt++)
          acc[mt][nt] = __builtin_amdgcn_mfma_f32_16x16x32_bf16(af[mt], bfr[nt], acc[mt][nt], 0, 0, 0);
    }

    #pragma unroll
    for (int mt=0; mt<4; mt++){
      #pragma unroll
      for (int reg=0; reg<4; reg++){
        int row = m0 + waveM + mt*16 + quad*4 + reg;   // bt index
        int b = row / 120, t = row % 120;
        #pragma unroll
        for (int nt=0; nt<4; nt++){
          int n = nc*128 + waveN + nt*16 + r16;
          u16 uv = f2bf(acc[mt][nt][reg]);
          if (n < 384){
            int tn = n >> 7, hh = (n >> 4) & 7, dd = n & 15;
            u16* base = (tn==0)? qt : (tn==1)? kt : vt;
            base[((((size_t)(b*8+hh)*24 + j)*120 + t) << 4) + dd] = uv;
          } else {
            int m2 = n - 384;
            int tn = m2 >> 7, hh = (m2 >> 4) & 7, dd = m2 & 15;
            u16* base = (tn==0)? qs : (tn==1)? ks : vs;
            base[((((size_t)row*8 + hh)*24 + j) << 4) + dd] = uv;
          }
        }
      }
    }
    __syncthreads();   // all waves done reading Bs before next chunk restages
  }
}

// ================= 8-phase 256x256 dual-projection GEMM (T2+T3+T4+T5) =================
// 512 threads = 8 waves (2M x 4N), per-wave 128x64 output, BK=64 split in two K-halves.
// LDS: 2 buffers x { A-Kh0 [256][32] | A-Kh1 | B-Kh0 | B-Kh1 } = 128 KiB.
// Counted vmcnt(10) twice per K-tile (never 0 in main loop); raw s_barrier only.
//
// Staging schedule (tile t, per phase one K-half = 2 global_load_lds/thread):
//   p0: A-Kh1(t+1) -> other buf     p1: B-Kh0(t+2) -> this buf (dead since p0)
//   p2: A-Kh0(t+2) -> this buf      p3: B-Kh1(t+2) -> this buf
// vmcnt(10) before end-barrier of p1 (guards Kh1(t) for p2) and of p3 (guards Kh0(t+1) for next p0).
// FIFO ledger verified: each wait retires exactly through the half needed by the next consuming phase.

__device__ __forceinline__ void stage_half(const u16* __restrict__ g, int kcol,
                                           u16* __restrict__ lsub, int lane, int wid){
  // sub-array [256][32] u16, contiguous 16 KiB; chunk = 16 rows = 1 KiB per wave-load
  #pragma unroll
  for (int i=0;i<2;i++){
    int row = wid*32 + i*16 + (lane>>2);
    int sw  = (((lane & 3) ^ ((lane>>3) & 3)) << 3);   // inverse of read swizzle ((row>>1)&3 == (lane>>3)&3)
    gload_lds16(&g[(size_t)row*3072 + kcol + sw], lsub + (wid*2+i)*512);
  }
}

__global__ __launch_bounds__(512)
void gemm_proj8(const u16* __restrict__ A0, const u16* __restrict__ B0, const float* __restrict__ b0,
                const u16* __restrict__ A1, const u16* __restrict__ B1, const float* __restrict__ b1v,
                const u16* __restrict__ resb, u16* __restrict__ O0, u16* __restrict__ O1,
                float* __restrict__ st0, float* __restrict__ st1)
{
  __shared__ __align__(16) u16 smem[65536];     // 128 KiB
  const int tid = threadIdx.x, lane = tid & 63, wid = tid >> 6;
  const int quad = lane >> 4, r16 = lane & 15;
  const int wm = wid >> 2, wn = wid & 3;
  const int m0 = blockIdx.x*256, n0 = blockIdx.y*256, z = blockIdx.z;
  const u16* Ag = (z ? A1 : A0) + (size_t)m0*3072;
  const u16* Bg = (z ? B1 : B0) + (size_t)n0*3072;
  const float* bias = z ? b1v : b0;
  u16* out = z ? O1 : O0;
  float* stp = z ? st1 : st0;

  // per-lane read swizzle: slot = quad ^ ((row>>1)&3); row = 16*c + r16 -> (row>>1)&3 == (r16>>1)&3
  const int soff = ((quad ^ ((r16>>1)&3)) << 3);
  const int arow = wm*128 + r16;
  const int brow = wn*64 + r16;

  f4 acc[8][4];
  #pragma unroll
  for (int i=0;i<8;i++)
    #pragma unroll
    for (int n=0;n<4;n++)
      #pragma unroll
      for (int q=0;q<4;q++) acc[i][n][q] = 0.f;

  // ---- prologue: 7 halves (14 loads/thread), FIFO order matters ----
  stage_half(Ag, 0,  smem + 0,             lane, wid);   // A-Kh0(0)
  stage_half(Bg, 0,  smem + 16384,         lane, wid);   // B-Kh0(0)
  stage_half(Ag, 32, smem + 8192,          lane, wid);   // A-Kh1(0)
  stage_half(Bg, 32, smem + 24576,         lane, wid);   // B-Kh1(0)
  stage_half(Ag, 64, smem + 32768 + 0,     lane, wid);   // A-Kh0(1)
  stage_half(Bg, 64, smem + 32768 + 16384, lane, wid);   // B-Kh0(1)
  stage_half(Bg, 96, smem + 32768 + 24576, lane, wid);   // B-Kh1(1)
  asm volatile("s_waitcnt vmcnt(10)" ::: "memory");      // oldest 4 loads (Kh0(0)) complete
  __builtin_amdgcn_s_barrier();

  const int NT = 48;                                     // K = 3072
  bf16x8 af[4], bf[4];

  for (int t=0; t<NT; ++t){
    u16* Ls = smem + ((t&1) ? 32768 : 0);
    u16* Lo = smem + ((t&1) ? 0 : 32768);
    const int c1 = ((t+1<NT)? t+1 : 0)*64;   // clamped: tail writes land in dead regions only
    const int c2 = ((t+2<NT)? t+2 : 0)*64;

    // ---------- p0: mg=0, kk=0 (reads A-Kh0 rows 0..63/half + B-Kh0) ----------
    #pragma unroll
    for (int i=0;i<4;i++) af[i] = *(const bf16x8*)&Ls[(arow + i*16)*32 + soff];
    #pragma unroll
    for (int n=0;n<4;n++) bf[n] = *(const bf16x8*)&Ls[16384 + (brow + n*16)*32 + soff];
    stage_half(Ag, c1+32, Lo + 8192, lane, wid);         // A-Kh1(t+1)
    __builtin_amdgcn_s_barrier();
    asm volatile("s_waitcnt lgkmcnt(0)" ::: "memory");
    __builtin_amdgcn_s_setprio(1);
    #pragma unroll
    for (int i=0;i<4;i++)
      #pragma unroll
      for (int n=0;n<4;n++)
        acc[i][n] = __builtin_amdgcn_mfma_f32_16x16x32_bf16(af[i], bf[n], acc[i][n], 0,0,0);
    __builtin_amdgcn_s_setprio(0);
    __builtin_amdgcn_s_barrier();

    // ---------- p1: mg=1, kk=0 (reads A-Kh0 rows 64..127/half; reuses bf) ----------
    #pragma unroll
    for (int i=0;i<4;i++) af[i] = *(const bf16x8*)&Ls[(arow + 64 + i*16)*32 + soff];
    stage_half(Bg, c2, Ls + 16384, lane, wid);           // B-Kh0(t+2), region dead since p0
    __builtin_amdgcn_s_barrier();
    asm volatile("s_waitcnt lgkmcnt(0)" ::: "memory");
    __builtin_amdgcn_s_setprio(1);
    #pragma unroll
    for (int i=0;i<4;i++)
      #pragma unroll
      for (int n=0;n<4;n++)
        acc[4+i][n] = __builtin_amdgcn_mfma_f32_16x16x32_bf16(af[i], bf[n], acc[4+i][n], 0,0,0);
    __builtin_amdgcn_s_setprio(0);
    asm volatile("s_waitcnt vmcnt(10)" ::: "memory");     // Kh1(t) complete before p2
    __builtin_amdgcn_s_barrier();

    // ---------- p2: mg=0, kk=1 (reads A-Kh1 + B-Kh1) ----------
    #pragma unroll
    for (int i=0;i<4;i++) af[i] = *(const bf16x8*)&Ls[8192 + (arow + i*16)*32 + soff];
    #pragma unroll
    for (int n=0;n<4;n++) bf[n] = *(const bf16x8*)&Ls[24576 + (brow + n*16)*32 + soff];
    stage_half(Ag, c2, Ls + 0, lane, wid);               // A-Kh0(t+2), region dead since p1
    __builtin_amdgcn_s_barrier();
    asm volatile("s_waitcnt lgkmcnt(0)" ::: "memory");
    __builtin_amdgcn_s_setprio(1);
    #pragma unroll
    for (int i=0;i<4;i++)
      #pragma unroll
      for (int n=0;n<4;n++)
        acc[i][n] = __builtin_amdgcn_mfma_f32_16x16x32_bf16(af[i], bf[n], acc[i][n], 0,0,0);
    __builtin_amdgcn_s_setprio(0);
    __builtin_amdgcn_s_barrier();

    // ---------- p3: mg=1, kk=1 ----------
    #pragma unroll
    for (int i=0;i<4;i++) af[i] = *(const bf16x8*)&Ls[8192 + (arow + 64 + i*16)*32 + soff];
    stage_half(Bg, c2+32, Ls + 24576, lane, wid);        // B-Kh1(t+2), region dead since p2
    __builtin_amdgcn_s_barrier();
    asm volatile("s_waitcnt lgkmcnt(0)" ::: "memory");
    __builtin_amdgcn_s_setprio(1);
    #pragma unroll
    for (int i=0;i<4;i++)
      #pragma unroll
      for (int n=0;n<4;n++)
        acc[4+i][n] = __builtin_amdgcn_mfma_f32_16x16x32_bf16(af[i], bf[n], acc[4+i][n], 0,0,0);
    __builtin_amdgcn_s_setprio(0);
    asm volatile("s_waitcnt vmcnt(10)" ::: "memory");     // Kh0(t+1) complete before next p0
    __builtin_amdgcn_s_barrier();
  }
  asm volatile("s_waitcnt vmcnt(0)" ::: "memory");        // drain clamped tail DMAs

  // ---------- epilogue: bias + residual + bf16 store + fused BN stats ----------
  float bv[4];
  #pragma unroll
  for (int n=0;n<4;n++) bv[n] = bias[n0 + wn*64 + n*16 + r16];
  float s[4] = {0,0,0,0}, s2[4] = {0,0,0,0};
  #pragma unroll
  for (int mf=0; mf<8; mf++){
    #pragma unroll
    for (int reg=0; reg<4; reg++){
      int grow = m0 + wm*128 + mf*16 + quad*4 + reg;
      #pragma unroll
      for (int n=0;n<4;n++){
        int gcol = n0 + wn*64 + n*16 + r16;
        size_t idx = (size_t)grow*3072 + gcol;
        float v = acc[mf][n][reg] + bv[n] + bf2f(resb[idx]);
        out[idx] = f2bf(v);
        s[n] += v; s2[n] += v*v;
      }
    }
  }
  #pragma unroll
  for (int n=0;n<4;n++){
    float a = s[n], b = s2[n];
    a += __shfl_xor(a, 16); a += __shfl_xor(a, 32);
    b += __shfl_xor(b, 16); b += __shfl_xor(b, 32);
    if (quad == 0){
      int col = n0 + wn*64 + n*16 + r16;
      atomicAdd(&stp[col], a);
      atomicAdd(&stp[3072 + col], b);
    }
  }
}

// ---------------- FF2 with fused BN stats ----------------
__global__ __launch_bounds__(256)
void gemm_ff2(const u16* __restrict__ A, const u16* __restrict__ B, const float* __restrict__ bias,
              const u16* __restrict__ resb, u16* __restrict__ out, float* __restrict__ stp)
{
  __shared__ __align__(16) u16 As[128*64];
  __shared__ __align__(16) u16 Bs[128*64];
  int m0 = blockIdx.x*128, n0 = blockIdx.y*128;
  f4 acc[4][4];
  gemm_tile(A + (size_t)m0*256, 256, B + (size_t)n0*256, 256, 256, acc, As, Bs);
  int lane = threadIdx.x & 63, wid = threadIdx.x >> 6;
  int waveM = (wid>>1)*64, waveN = (wid&1)*64;
  int quad = lane>>4, r16 = lane&15;
  float s[4] = {0,0,0,0}, s2[4] = {0,0,0,0};
  #pragma unroll
  for (int mt=0; mt<4; mt++){
    #pragma unroll
    for (int reg=0; reg<4; reg++){
      int grow = m0 + waveM + mt*16 + quad*4 + reg;
      #pragma unroll
      for (int nt=0; nt<4; nt++){
        int gcol = n0 + waveN + nt*16 + r16;
        size_t idx = (size_t)grow*3072 + gcol;
        float v = acc[mt][nt][reg] + bias[gcol] + bf2f(resb[idx]);
        out[idx] = f2bf(v);
        s[nt] += v; s2[nt] += v*v;
      }
    }
  }
  #pragma unroll
  for (int nt=0; nt<4; nt++){
    float a = s[nt], b = s2[nt];
    a += __shfl_xor(a, 16); a += __shfl_xor(a, 32);
    b += __shfl_xor(b, 16); b += __shfl_xor(b, 32);
    if (quad == 0){
      int col = n0 + waveN + nt*16 + r16;
      atomicAdd(&stp[col], a);
      atomicAdd(&stp[3072 + col], b);
    }
  }
}

// FF1: out bf16 = relu(A@B^T + bias)
__global__ __launch_bounds__(256)
void gemm_relu(const u16* __restrict__ A, const u16* __restrict__ B, int K, int N,
               const float* __restrict__ bias, u16* __restrict__ out)
{
  __shared__ __align__(16) u16 As[128*64];
  __shared__ __align__(16) u16 Bs[128*64];
  int m0 = blockIdx.x*128, n0 = blockIdx.y*128;
  f4 acc[4][4];
  gemm_tile(A + (size_t)m0*K, K, B + (size_t)n0*K, K, K, acc, As, Bs);
  int lane = threadIdx.x & 63, wid = threadIdx.x >> 6;
  int waveM = (wid>>1)*64, waveN = (wid&1)*64;
  int quad = lane>>4, r16 = lane&15;
  #pragma unroll
  for (int mt=0; mt<4; mt++){
    #pragma unroll
    for (int reg=0; reg<4; reg++){
      int grow = m0 + waveM + mt*16 + quad*4 + reg;
      #pragma unroll
      for (int nt=0; nt<4; nt++){
        int gcol = n0 + waveN + nt*16 + r16;
        float v = acc[mt][nt][reg] + bias[gcol];
        out[(size_t)grow*N + gcol] = f2bf(v > 0.f ? v : 0.f);
      }
    }
  }
}

// ---------------- merged attention: blocks [0,6144) temporal MFMA, [6144,9984) spatial ----------------
__global__ __launch_bounds__(256)
void attn_both(const u16* __restrict__ qt, const u16* __restrict__ kt,
               const u16* __restrict__ vt, u16* __restrict__ ta,
               const u16* __restrict__ qsp, const u16* __restrict__ ksp,
               const u16* __restrict__ vsp, u16* __restrict__ sa)
{
  __shared__ __align__(16) char smem[39168];
  int tid = threadIdx.x, lane = tid & 63, wid = tid >> 6;
  int quad = lane >> 4, r16 = lane & 15;

  if (blockIdx.x < 6144){
    // ---- temporal: one block per (b,h,j), T=120 pad 128, d=16 pad 32 ----
    u16* P  = (u16*)smem;             // 128*LDP
    u16* Vt = (u16*)(smem + 34816);   // 16*LDP
    int blk = blockIdx.x;
    int b = blk / 192;
    int rem = blk % 192;
    int h = rem / 24, j = rem % 24;
    const u16* qb = qt + (size_t)blk*1920;
    const u16* kb = kt + (size_t)blk*1920;
    const u16* vb = vt + (size_t)blk*1920;

    for (int e = tid; e < 1920; e += 256){
      int s = e >> 4, dd = e & 15;
      Vt[dd*LDP + s] = vb[e];
    }
    if (tid < 128){ int dd = tid >> 3, s = 120 + (tid & 7); Vt[dd*LDP + s] = 0; }
    __syncthreads();

    bf16x8 zv;
    #pragma unroll
    for (int i=0;i<8;i++) zv[i] = (__bf16)0.f;

    const int m0 = wid * 32;
    bf16x8 qf[2];
    #pragma unroll
    for (int mt=0; mt<2; mt++){
      int row = m0 + mt*16 + r16; if (row > 119) row = 119;
      qf[mt] = (quad < 2) ? *(const bf16x8*)&qb[row*16 + (quad&1)*8] : zv;
    }

    f4 S[2][8];
    #pragma unroll
    for (int nt=0; nt<8; nt++){
      int col = nt*16 + r16; int colc = col > 119 ? 119 : col;
      bf16x8 kf = (quad < 2) ? *(const bf16x8*)&kb[colc*16 + (quad&1)*8] : zv;
      #pragma unroll
      for (int mt=0; mt<2; mt++){
        f4 zz = {0.f, 0.f, 0.f, 0.f};
        S[mt][nt] = __builtin_amdgcn_mfma_f32_16x16x32_bf16(qf[mt], kf, zz, 0, 0, 0);
      }
    }

    #pragma unroll
    for (int mt=0; mt<2; mt++)
      #pragma unroll
      for (int nt=0; nt<8; nt++)
        #pragma unroll
        for (int reg=0; reg<4; reg++){
          int c = nt*16 + r16;
          int r = m0 + mt*16 + quad*4 + reg;
          float v = S[mt][nt][reg] * 0.25f;
          S[mt][nt][reg] = (c > r || c >= 120) ? -1e30f : v;
        }

    float Zr[2][4];
    #pragma unroll
    for (int mt=0; mt<2; mt++)
      #pragma unroll
      for (int reg=0; reg<4; reg++){
        float m = -1e30f;
        #pragma unroll
        for (int nt=0; nt<8; nt++) m = fmaxf(m, S[mt][nt][reg]);
        #pragma unroll
        for (int off=1; off<16; off<<=1) m = fmaxf(m, __shfl_xor(m, off, 16));
        float z = 0.f;
        #pragma unroll
        for (int nt=0; nt<8; nt++){
          float e = __expf(S[mt][nt][reg] - m);
          S[mt][nt][reg] = e;
          z += e;
        }
        #pragma unroll
        for (int off=1; off<16; off<<=1) z += __shfl_xor(z, off, 16);
        Zr[mt][reg] = z;
      }

    #pragma unroll
    for (int mt=0; mt<2; mt++)
      #pragma unroll
      for (int nt=0; nt<8; nt++)
        #pragma unroll
        for (int reg=0; reg<4; reg++)
          P[(m0 + mt*16 + quad*4 + reg)*LDP + nt*16 + r16] = f2bf(S[mt][nt][reg]);
    __syncthreads();

    f4 O[2];
    #pragma unroll
    for (int mt=0; mt<2; mt++){ O[mt][0]=0.f; O[mt][1]=0.f; O[mt][2]=0.f; O[mt][3]=0.f; }
    #pragma unroll
    for (int kt8=0; kt8<4; kt8++){
      bf16x8 vf = *(const bf16x8*)&Vt[r16*LDP + kt8*32 + quad*8];
      #pragma unroll
      for (int mt=0; mt<2; mt++){
        bf16x8 pf = *(const bf16x8*)&P[(m0 + mt*16 + r16)*LDP + kt8*32 + quad*8];
        O[mt] = __builtin_amdgcn_mfma_f32_16x16x32_bf16(pf, vf, O[mt], 0, 0, 0);
      }
    }

    #pragma unroll
    for (int mt=0; mt<2; mt++)
      #pragma unroll
      for (int reg=0; reg<4; reg++){
        int r = m0 + mt*16 + quad*4 + reg;
        if (r < 120){
          size_t idx = (size_t)(b*120 + r)*3072 + h*384 + j*16 + r16;
          ta[idx] = f2bf(O[mt][reg] / Zr[mt][reg]);
        }
      }
  } else {
    // ---- spatial: one block per (b,t); threads 0..191 = (h,j); softmax over 24 joints ----
    float* Ks = (float*)smem;            // 3072
    float* Vs = (float*)(smem + 12288);  // 3072
    int bt = blockIdx.x - 6144;
    size_t base = (size_t)bt * 3072;
    for (int c = tid; c < 384; c += 256){
      bf16x8 kv = *(const bf16x8*)&ksp[base + c*8];
      bf16x8 vv = *(const bf16x8*)&vsp[base + c*8];
      #pragma unroll
      for (int i=0;i<8;i++){ Ks[c*8+i] = (float)kv[i]; Vs[c*8+i] = (float)vv[i]; }
    }
    __syncthreads();
    if (tid < 192){
      int h = tid / 24, j = tid % 24;
      float q[16];
      #pragma unroll
      for (int d2=0; d2<16; d2++) q[d2] = bf2f(qsp[base + h*384 + j*16 + d2]);
      float sc[24], mx = -1e30f;
      #pragma unroll
      for (int kk=0; kk<24; kk++){
        float dot = 0.f;
        #pragma unroll
        for (int d2=0; d2<16; d2++) dot += q[d2]*Ks[h*384 + kk*16 + d2];
        sc[kk] = dot * 0.25f;
        mx = fmaxf(mx, sc[kk]);
      }
      float Z = 0.f, acc[16];
      #pragma unroll
      for (int d2=0; d2<16; d2++) acc[d2] = 0.f;
      #pragma unroll
      for (int kk=0; kk<24; kk++){
        float w = __expf(sc[kk] - mx);
        Z += w;
        #pragma unroll
        for (int d2=0; d2<16; d2++) acc[d2] += w*Vs[h*384 + kk*16 + d2];
      }
      float inv = 1.f / Z;
      #pragma unroll
      for (int d2=0; d2<16; d2++) sa[base + h*384 + j*16 + d2] = f2bf(acc[d2]*inv);
    }
  }
}

// ---------------- batchnorm ----------------
// blocks 0..11: temporal coefs; 12..23: spatial coefs
__global__ void bn_coef2(const float* __restrict__ accT, const float* __restrict__ gT,
                         const float* __restrict__ bT, float* __restrict__ cT,
                         const float* __restrict__ accS, const float* __restrict__ gS,
                         const float* __restrict__ bS, float* __restrict__ cS){
  int isS = blockIdx.x >= 12;
  const float* acc = isS ? accS : accT;
  const float* g   = isS ? gS : gT;
  const float* b   = isS ? bS : bT;
  float* coef      = isS ? cS : cT;
  int c = (blockIdx.x % 12)*256 + threadIdx.x;
  float mean = acc[c] * (1.f/3840.f);
  float var  = acc[3072+c] * (1.f/3840.f) - mean*mean;
  float sc = g[c] * rsqrtf(var + 1e-5f);
  coef[c] = sc;
  coef[3072+c] = b[c] - mean*sc;
}

__global__ void bn_coef(const float* __restrict__ acc, const float* __restrict__ g,
                        const float* __restrict__ b, float* __restrict__ coef){
  int c = blockIdx.x*256 + threadIdx.x;
  float mean = acc[c] * (1.f/3840.f);
  float var  = acc[3072+c] * (1.f/3840.f) - mean*mean;
  float sc = g[c] * rsqrtf(var + 1e-5f);
  coef[c] = sc;
  coef[3072+c] = b[c] - mean*sc;
}

// att = BN_t(Yt) + BN_s(Ys), vectorized x4  (channel = (i*4) mod 3072 — NOT a pow2 mask!)
__global__ void bn_apply2(const u16* __restrict__ Ytb, const u16* __restrict__ Ysb,
                          const float* __restrict__ ct, const float* __restrict__ cs,
                          u16* __restrict__ attB){
  int i = blockIdx.x*256 + threadIdx.x;     // < NX/4
  int c = (i*4) % 3072;
  u16x4 yt = *(const u16x4*)&Ytb[i*4];
  u16x4 ys = *(const u16x4*)&Ysb[i*4];
  u16x4 o;
  #pragma unroll
  for (int k=0;k<4;k++){
    float a = bf2f(yt[k])*ct[c+k] + ct[3072+c+k] + bf2f(ys[k])*cs[c+k] + cs[3072+c+k];
    o[k] = f2bf(a);
  }
  *(u16x4*)&attB[i*4] = o;
}

__global__ void bn_out(const u16* __restrict__ Yfb, const float* __restrict__ cf,
                       float* __restrict__ out){
  int i = blockIdx.x*256 + threadIdx.x;     // < NX/4
  int c = (i*4) % 3072;
  u16x4 yf = *(const u16x4*)&Yfb[i*4];
  float4v o;
  #pragma unroll
  for (int k=0;k<4;k++) o[k] = bf2f(yf[k])*cf[c+k] + cf[3072+c+k];
  *(float4v*)&out[i*4] = o;
}

// ---------------- launch ----------------
extern "C" void kernel_launch(void* const* d_in, const int* in_sizes, int n_in,
                              void* d_out, int out_size, void* d_ws, size_t ws_size,
                              hipStream_t stream)
{
  const float* src  = (const float*)d_in[0];
  const float* Wq_t = (const float*)d_in[1];
  const float* Wk_t = (const float*)d_in[2];
  const float* Wv_t = (const float*)d_in[3];
  const float* Wp_t = (const float*)d_in[4];
  const float* bp_t = (const float*)d_in[5];
  const float* g_t  = (const float*)d_in[6];
  const float* b_t  = (const float*)d_in[7];
  const float* Wq_s = (const float*)d_in[8];
  const float* Wk_s = (const float*)d_in[9];
  const float* Wv_s = (const float*)d_in[10];
  const float* Wp_s = (const float*)d_in[11];
  const float* bp_s = (const float*)d_in[12];
  const float* g_s  = (const float*)d_in[13];
  const float* b_s  = (const float*)d_in[14];
  const float* W1   = (const float*)d_in[15];
  const float* b1   = (const float*)d_in[16];
  const float* W2   = (const float*)d_in[17];
  const float* b2   = (const float*)d_in[18];
  const float* g_f  = (const float*)d_in[19];
  const float* b_f  = (const float*)d_in[20];

  char* ws = (char*)d_ws;
  u16* x_bf  = (u16*)(ws + 0ull);
  u16* wptb  = (u16*)(ws + 23592960ull);
  u16* wpsb  = (u16*)(ws + 42467328ull);
  u16* w1b   = (u16*)(ws + 61341696ull);
  u16* w2b   = (u16*)(ws + 62914560ull);
  u16* wcat  = (u16*)(ws + 64487424ull);
  u16* qt    = (u16*)(ws + 69206016ull);
  u16* kt    = qt + NX;
  u16* vt    = kt + NX;
  u16* qs    = vt + NX;
  u16* ks    = qs + NX;
  u16* vs    = ks + NX;
  u16* tab   = (u16*)(ws + 210763776ull);
  u16* sab   = (u16*)(ws + 234356736ull);
  float* accT = (float*)(ws + 257949696ull);
  float* accS = accT + 6144;
  float* accF = accS + 6144;
  float* cT   = accF + 6144;
  float* cS   = cT + 6144;
  float* cF   = cS + 6144;
  // bf16 aliases over dead regions
  u16* Ytb  = qt;   // dead after attention
  u16* Ysb  = kt;
  u16* attB = vt;
  u16* Yfb  = qs;
  u16* h1   = wcat; // dead after gemm_qkv
  float* out = (float*)d_out;

  // 1. fused prep (zero accs + conversions + weight pack)
  k_prep<<<40776, 256, 0, stream>>>(src, x_bf, Wp_t, wptb, Wp_s, wpsb, W1, w1b, W2, w2b,
                                    Wq_t, Wk_t, Wv_t, Wq_s, Wk_s, Wv_s, wcat, accT);
  // 2. QKV projections (per joint; A staged once, 6 B-chunks)
  gemm_qkv<<<dim3(30,24), 256, 0, stream>>>(x_bf, wcat, qt, kt, vt, qs, ks, vs);
  // 3. both attentions in one launch
  attn_both<<<9984, 256, 0, stream>>>(qt, kt, vt, tab, qs, ks, vs, sab);
  // 4. output projections + residual + fused BN stats (8-phase 256^2 pipeline)
  gemm_proj8<<<dim3(15,12,2), 512, 0, stream>>>(tab, wptb, bp_t, sab, wpsb, bp_s,
                                                x_bf, Ytb, Ysb, accT, accS);
  // 5. BN coefs (t+s) + fused apply
  bn_coef2<<<24, 256, 0, stream>>>(accT, g_t, b_t, cT, accS, g_s, b_s, cS);
  bn_apply2<<<11520, 256, 0, stream>>>(Ytb, Ysb, cT, cS, attB);
  // 6. feed-forward
  gemm_relu<<<dim3(30,2), 256, 0, stream>>>(attB, w1b, 3072, 256, b1, h1);
  gemm_ff2<<<dim3(30,24), 256, 0, stream>>>(h1, w2b, b2, attB, Yfb, accF);
  // 7. final BN
  bn_coef<<<12, 256, 0, stream>>>(accF, g_f, b_f, cF);
  bn_out<<<11520, 256, 0, stream>>>(Yfb, cF, out);
}

// Round 2
// 660.882 us; speedup vs baseline: 1.0689x; 1.0152x over previous
//
#include <hip/hip_runtime.h>

typedef unsigned short u16;
typedef __bf16 bf16x8 __attribute__((ext_vector_type(8)));
typedef float f4 __attribute__((ext_vector_type(4)));
typedef float float4v __attribute__((ext_vector_type(4)));
typedef u16 u16x4 __attribute__((ext_vector_type(4)));

#define NX 11796480   // B*T*D = 3840*3072
#define LDP 136       // padded LDS row (u16 elems) for P / Vt in temporal attn

__device__ __forceinline__ float bf2f(u16 u){ __bf16 h = __builtin_bit_cast(__bf16, u); return (float)h; }
__device__ __forceinline__ u16 f2bf(float f){ __bf16 h = (__bf16)f; return __builtin_bit_cast(u16, h); }

__device__ __forceinline__ void gload_lds16(const u16* g, u16* l){
  __builtin_amdgcn_global_load_lds((const __attribute__((address_space(1))) void*)g,
                                   (__attribute__((address_space(3))) void*)l, 16, 0, 0);
}

// ---------------- fused prep: zero BN accs + all fp32->bf16 conversions + QKV weight pack ----------------
__device__ __forceinline__ void cvt4seg(const float* __restrict__ in, u16* __restrict__ out, int i){
  float4v v = *(const float4v*)&in[i*4];
  u16x4 o;
  o[0]=f2bf(v[0]); o[1]=f2bf(v[1]); o[2]=f2bf(v[2]); o[3]=f2bf(v[3]);
  *(u16x4*)&out[i*4] = o;
}

// total items = 18432 + 2949120 + 2359296 + 2359296 + 196608 + 196608 + 2359296 = 10438656 = 40776*256
__global__ void k_prep(const float* __restrict__ src, u16* __restrict__ x_bf,
                       const float* __restrict__ wpt, u16* __restrict__ wptb,
                       const float* __restrict__ wps, u16* __restrict__ wpsb,
                       const float* __restrict__ w1,  u16* __restrict__ w1b,
                       const float* __restrict__ w2,  u16* __restrict__ w2b,
                       const float* __restrict__ wqt, const float* __restrict__ wkt,
                       const float* __restrict__ wvt, const float* __restrict__ wqs,
                       const float* __restrict__ wks, const float* __restrict__ wvs,
                       u16* __restrict__ wcat, float* __restrict__ accs){
  int i = blockIdx.x*256 + threadIdx.x;
  if (i < 18432){ accs[i] = 0.f; return; }
  i -= 18432;
  if (i < 2949120){ cvt4seg(src, x_bf, i); return; }
  i -= 2949120;
  if (i < 2359296){ cvt4seg(wpt, wptb, i); return; }
  i -= 2359296;
  if (i < 2359296){ cvt4seg(wps, wpsb, i); return; }
  i -= 2359296;
  if (i < 196608){ cvt4seg(w1, w1b, i); return; }
  i -= 196608;
  if (i < 196608){ cvt4seg(w2, w2b, i); return; }
  i -= 196608;
  // pack Wq_t|Wk_t|Wv_t|Wq_s|Wk_s|Wv_s into (J=24, N=768, K=128) row-major bf16
  int e = i & 127;
  int n = (i >> 7) % 768;
  int j = i / (768*128);
  float v;
  if (n < 512){
    int tn = n >> 7, hh = (n >> 4) & 7, dd = n & 15;
    const float* W = (tn==0)? wqt : (tn==1)? wkt : (tn==2)? wvt : wqs;  // (H,J,d,E)
    v = W[(((hh*24 + j)*16 + dd) << 7) + e];
  } else {
    int m = n - 512;
    int tn = m >> 7, hh = (m >> 4) & 7, dd = m & 15;
    const float* W = (tn==0)? wks : wvs;                                // (H,d,E)
    v = W[((hh*16 + dd) << 7) + e];
  }
  wcat[i] = f2bf(v);
}

// ---------------- MFMA GEMM core (BK=64): C[128,128] tile of A[M,K]*B[N,K]^T ----------------
// (kept for gemm_relu / gemm_ff2 — small-K GEMMs)
__device__ __forceinline__ void gemm_tile(const u16* __restrict__ Ab, int lda,
                                          const u16* __restrict__ Bb, int ldb,
                                          int K, f4 acc[4][4], u16* As, u16* Bs)
{
  const int tid  = threadIdx.x;
  const int lane = tid & 63;
  const int wid  = tid >> 6;
  const int waveM = (wid >> 1) * 64;
  const int waveN = (wid & 1) * 64;
  const int quad = lane >> 4;
  const int r16  = lane & 15;
  const int srow = tid >> 3;                       // 0..31
  const int gcol = ((tid & 7) ^ (srow & 7)) * 8;   // swizzled source column

  #pragma unroll
  for (int mt=0; mt<4; mt++)
    #pragma unroll
    for (int nt=0; nt<4; nt++)
      #pragma unroll
      for (int q=0; q<4; q++) acc[mt][nt][q] = 0.f;

  for (int k0 = 0; k0 < K; k0 += 64){
    __syncthreads();
    #pragma unroll
    for (int i=0; i<4; i++){
      int row = srow + i*32;
      gload_lds16(&Ab[(size_t)row*lda + k0 + gcol], As + wid*512 + i*2048);
      gload_lds16(&Bb[(size_t)row*ldb + k0 + gcol], Bs + wid*512 + i*2048);
    }
    __builtin_amdgcn_s_waitcnt(0);
    __syncthreads();
    #pragma unroll
    for (int kk=0; kk<2; kk++){
      bf16x8 af[4], bfr[4];
      const int soff = ((kk*4 + quad) ^ (r16 & 7)) * 8;   // swizzled read slot
      #pragma unroll
      for (int mt=0; mt<4; mt++)
        af[mt] = *(const bf16x8*)&As[(waveM + mt*16 + r16)*64 + soff];
      #pragma unroll
      for (int nt=0; nt<4; nt++)
        bfr[nt] = *(const bf16x8*)&Bs[(waveN + nt*16 + r16)*64 + soff];
      #pragma unroll
      for (int mt=0; mt<4; mt++)
        #pragma unroll
        for (int nt=0; nt<4; nt++)
          acc[mt][nt] = __builtin_amdgcn_mfma_f32_16x16x32_bf16(af[mt], bfr[nt], acc[mt][nt], 0, 0, 0);
    }
  }
  __syncthreads();
}

// ---------------- QKV GEMM: stage A once, loop 6 B-chunks of 128 (N=768 total) ----------------
__global__ __launch_bounds__(256)
void gemm_qkv(const u16* __restrict__ x, const u16* __restrict__ wcat,
              u16* __restrict__ qt, u16* __restrict__ kt, u16* __restrict__ vt,
              u16* __restrict__ qs, u16* __restrict__ ks, u16* __restrict__ vs)
{
  __shared__ __align__(16) u16 As[128*128];
  __shared__ __align__(16) u16 Bs[128*128];
  int m0 = blockIdx.x*128, j = blockIdx.y;
  const u16* Ab = x + (size_t)m0*3072 + j*128;
  const u16* Bbase = wcat + (size_t)j*98304;
  int tid = threadIdx.x, lane = tid & 63, wid = tid >> 6;
  int quad = lane >> 4, r16 = lane & 15;
  int srow16 = tid >> 4;                   // 0..15
  int cslot  = tid & 15;
  int gcol   = (cslot ^ srow16) * 8;       // swizzled source column

  #pragma unroll
  for (int it=0; it<8; it++){
    int row = srow16 + it*16;
    gload_lds16(&Ab[(size_t)row*3072 + gcol], As + tid*8 + it*2048);
  }

  int waveM = (wid>>1)*64, waveN = (wid&1)*64;

  for (int nc=0; nc<6; nc++){
    const u16* Bb = Bbase + (size_t)(nc*128)*128;
    #pragma unroll
    for (int it=0; it<8; it++){
      int row = srow16 + it*16;
      gload_lds16(&Bb[(size_t)row*128 + gcol], Bs + tid*8 + it*2048);
    }
    __builtin_amdgcn_s_waitcnt(0);
    __syncthreads();

    f4 acc[4][4];
    #pragma unroll
    for (int mt=0; mt<4; mt++)
      #pragma unroll
      for (int nt=0; nt<4; nt++)
        #pragma unroll
        for (int q=0; q<4; q++) acc[mt][nt][q] = 0.f;

    #pragma unroll
    for (int kk=0; kk<4; kk++){
      bf16x8 af[4], bfr[4];
      const int soff = ((kk*4 + quad) ^ r16) * 8;
      #pragma unroll
      for (int mt=0; mt<4; mt++)
        af[mt] = *(const bf16x8*)&As[(waveM + mt*16 + r16)*128 + soff];
      #pragma unroll
      for (int nt=0; nt<4; nt++)
        bfr[nt] = *(const bf16x8*)&Bs[(waveN + nt*16 + r16)*128 + soff];
      #pragma unroll
      for (int mt=0; mt<4; mt++)
        #pragma unroll
        for (int nt=0; nt<4; nt++)
          acc[mt][nt] = __builtin_amdgcn_mfma_f32_16x16x32_bf16(af[mt], bfr[nt], acc[mt][nt], 0, 0, 0);
    }

    #pragma unroll
    for (int mt=0; mt<4; mt++){
      #pragma unroll
      for (int reg=0; reg<4; reg++){
        int row = m0 + waveM + mt*16 + quad*4 + reg;   // bt index
        int b = row / 120, t = row % 120;
        #pragma unroll
        for (int nt=0; nt<4; nt++){
          int n = nc*128 + waveN + nt*16 + r16;
          u16 uv = f2bf(acc[mt][nt][reg]);
          if (n < 384){
            int tn = n >> 7, hh = (n >> 4) & 7, dd = n & 15;
            u16* base = (tn==0)? qt : (tn==1)? kt : vt;
            base[((((size_t)(b*8+hh)*24 + j)*120 + t) << 4) + dd] = uv;
          } else {
            int m2 = n - 384;
            int tn = m2 >> 7, hh = (m2 >> 4) & 7, dd = m2 & 15;
            u16* base = (tn==0)? qs : (tn==1)? ks : vs;
            base[((((size_t)row*8 + hh)*24 + j) << 4) + dd] = uv;
          }
        }
      }
    }
    __syncthreads();   // all waves done reading Bs before next chunk restages
  }
}

// ================= 8-phase 256x256 dual-projection GEMM (T2+T3+T4, reduced-lockstep) =================
// 512 threads = 8 waves (2M x 4N), per-wave 128x64 output, BK=64 split in two K-halves.
// LDS: 2 buffers x { A-Kh0 [256][32] | A-Kh1 | B-Kh0 | B-Kh1 } = 128 KiB.
//
// R2 change: only the 4 LOAD-BEARING barriers per K-tile are kept (each either frees an LDS
// region for the next DMA overwrite or publishes a vmcnt-retired DMA); the 4 begin-barriers
// and the explicit lgkmcnt(0) drains are removed so the compiler emits fine-grained lgkmcnt
// and waves can slide (one wave's ds_read/DMA issue overlaps its SIMD-partner's MFMAs).
//   LB1 (p0 end): all waves consumed B-Kh0(t)  -> p1 may DMA B-Kh0(t+2) over it
//   LB2 (p1 end, after vmcnt(10)): Kh1(t) DMA published; A-Kh0(t) consumed -> p2 DMA
//   LB3 (p2 end): B-Kh1(t) consumed -> p3 DMA
//   LB4 (p3 end, after vmcnt(10)): Kh0(t+1) DMA published; A-Kh1(t) consumed -> next p0 DMA

__device__ __forceinline__ void stage_half(const u16* __restrict__ g, int kcol,
                                           u16* __restrict__ lsub, int lane, int wid){
  // sub-array [256][32] u16, contiguous 16 KiB; chunk = 16 rows = 1 KiB per wave-load
  #pragma unroll
  for (int i=0;i<2;i++){
    int row = wid*32 + i*16 + (lane>>2);
    int sw  = (((lane & 3) ^ ((lane>>3) & 3)) << 3);   // inverse of read swizzle ((row>>1)&3 == (lane>>3)&3)
    gload_lds16(&g[(size_t)row*3072 + kcol + sw], lsub + (wid*2+i)*512);
  }
}

__global__ __launch_bounds__(512)
void gemm_proj8(const u16* __restrict__ A0, const u16* __restrict__ B0, const float* __restrict__ b0,
                const u16* __restrict__ A1, const u16* __restrict__ B1, const float* __restrict__ b1v,
                const u16* __restrict__ resb, u16* __restrict__ O0, u16* __restrict__ O1,
                float* __restrict__ st0, float* __restrict__ st1)
{
  __shared__ __align__(16) u16 smem[65536];     // 128 KiB
  const int tid = threadIdx.x, lane = tid & 63, wid = tid >> 6;
  const int quad = lane >> 4, r16 = lane & 15;
  const int wm = wid >> 2, wn = wid & 3;
  const int m0 = blockIdx.x*256, n0 = blockIdx.y*256, z = blockIdx.z;
  const u16* Ag = (z ? A1 : A0) + (size_t)m0*3072;
  const u16* Bg = (z ? B1 : B0) + (size_t)n0*3072;
  const float* bias = z ? b1v : b0;
  u16* out = z ? O1 : O0;
  float* stp = z ? st1 : st0;

  // per-lane read swizzle: slot = quad ^ ((row>>1)&3); row = 16*c + r16 -> (row>>1)&3 == (r16>>1)&3
  const int soff = ((quad ^ ((r16>>1)&3)) << 3);
  const int arow = wm*128 + r16;
  const int brow = wn*64 + r16;

  f4 acc[8][4];
  #pragma unroll
  for (int i=0;i<8;i++)
    #pragma unroll
    for (int n=0;n<4;n++)
      #pragma unroll
      for (int q=0;q<4;q++) acc[i][n][q] = 0.f;

  // ---- prologue: 7 halves (14 loads/thread), FIFO order matters ----
  stage_half(Ag, 0,  smem + 0,             lane, wid);   // A-Kh0(0)
  stage_half(Bg, 0,  smem + 16384,         lane, wid);   // B-Kh0(0)
  stage_half(Ag, 32, smem + 8192,          lane, wid);   // A-Kh1(0)
  stage_half(Bg, 32, smem + 24576,         lane, wid);   // B-Kh1(0)
  stage_half(Ag, 64, smem + 32768 + 0,     lane, wid);   // A-Kh0(1)
  stage_half(Bg, 64, smem + 32768 + 16384, lane, wid);   // B-Kh0(1)
  stage_half(Bg, 96, smem + 32768 + 24576, lane, wid);   // B-Kh1(1)
  asm volatile("s_waitcnt vmcnt(10)" ::: "memory");      // oldest 4 loads (Kh0(0)) complete
  __builtin_amdgcn_s_barrier();

  const int NT = 48;                                     // K = 3072
  bf16x8 af[4], bf[4];

  for (int t=0; t<NT; ++t){
    u16* Ls = smem + ((t&1) ? 32768 : 0);
    u16* Lo = smem + ((t&1) ? 0 : 32768);
    const int c1 = ((t+1<NT)? t+1 : 0)*64;   // clamped: tail writes land in dead regions only
    const int c2 = ((t+2<NT)? t+2 : 0)*64;

    // ---------- p0: mg=0, kk=0 (reads A-Kh0 rows 0..63/half + B-Kh0) ----------
    #pragma unroll
    for (int i=0;i<4;i++) af[i] = *(const bf16x8*)&Ls[(arow + i*16)*32 + soff];
    #pragma unroll
    for (int n=0;n<4;n++) bf[n] = *(const bf16x8*)&Ls[16384 + (brow + n*16)*32 + soff];
    stage_half(Ag, c1+32, Lo + 8192, lane, wid);         // A-Kh1(t+1)
    __builtin_amdgcn_s_setprio(1);
    #pragma unroll
    for (int i=0;i<4;i++)
      #pragma unroll
      for (int n=0;n<4;n++)
        acc[i][n] = __builtin_amdgcn_mfma_f32_16x16x32_bf16(af[i], bf[n], acc[i][n], 0,0,0);
    __builtin_amdgcn_s_setprio(0);
    __builtin_amdgcn_s_barrier();                        // LB1

    // ---------- p1: mg=1, kk=0 (reads A-Kh0 rows 64..127/half; reuses bf) ----------
    #pragma unroll
    for (int i=0;i<4;i++) af[i] = *(const bf16x8*)&Ls[(arow + 64 + i*16)*32 + soff];
    stage_half(Bg, c2, Ls + 16384, lane, wid);           // B-Kh0(t+2), region freed by LB1
    __builtin_amdgcn_s_setprio(1);
    #pragma unroll
    for (int i=0;i<4;i++)
      #pragma unroll
      for (int n=0;n<4;n++)
        acc[4+i][n] = __builtin_amdgcn_mfma_f32_16x16x32_bf16(af[i], bf[n], acc[4+i][n], 0,0,0);
    __builtin_amdgcn_s_setprio(0);
    asm volatile("s_waitcnt vmcnt(10)" ::: "memory");     // Kh1(t) complete before p2
    __builtin_amdgcn_s_barrier();                        // LB2

    // ---------- p2: mg=0, kk=1 (reads A-Kh1 + B-Kh1) ----------
    #pragma unroll
    for (int i=0;i<4;i++) af[i] = *(const bf16x8*)&Ls[8192 + (arow + i*16)*32 + soff];
    #pragma unroll
    for (int n=0;n<4;n++) bf[n] = *(const bf16x8*)&Ls[24576 + (brow + n*16)*32 + soff];
    stage_half(Ag, c2, Ls + 0, lane, wid);               // A-Kh0(t+2), region freed by LB2
    __builtin_amdgcn_s_setprio(1);
    #pragma unroll
    for (int i=0;i<4;i++)
      #pragma unroll
      for (int n=0;n<4;n++)
        acc[i][n] = __builtin_amdgcn_mfma_f32_16x16x32_bf16(af[i], bf[n], acc[i][n], 0,0,0);
    __builtin_amdgcn_s_setprio(0);
    __builtin_amdgcn_s_barrier();                        // LB3

    // ---------- p3: mg=1, kk=1 ----------
    #pragma unroll
    for (int i=0;i<4;i++) af[i] = *(const bf16x8*)&Ls[8192 + (arow + 64 + i*16)*32 + soff];
    stage_half(Bg, c2+32, Ls + 24576, lane, wid);        // B-Kh1(t+2), region freed by LB3
    __builtin_amdgcn_s_setprio(1);
    #pragma unroll
    for (int i=0;i<4;i++)
      #pragma unroll
      for (int n=0;n<4;n++)
        acc[4+i][n] = __builtin_amdgcn_mfma_f32_16x16x32_bf16(af[i], bf[n], acc[4+i][n], 0,0,0);
    __builtin_amdgcn_s_setprio(0);
    asm volatile("s_waitcnt vmcnt(10)" ::: "memory");     // Kh0(t+1) complete before next p0
    __builtin_amdgcn_s_barrier();                        // LB4
  }
  asm volatile("s_waitcnt vmcnt(0)" ::: "memory");        // drain clamped tail DMAs

  // ---------- epilogue: bias + residual + bf16 store + fused BN stats ----------
  float bv[4];
  #pragma unroll
  for (int n=0;n<4;n++) bv[n] = bias[n0 + wn*64 + n*16 + r16];
  float s[4] = {0,0,0,0}, s2[4] = {0,0,0,0};
  #pragma unroll
  for (int mf=0; mf<8; mf++){
    #pragma unroll
    for (int reg=0; reg<4; reg++){
      int grow = m0 + wm*128 + mf*16 + quad*4 + reg;
      #pragma unroll
      for (int n=0;n<4;n++){
        int gcol = n0 + wn*64 + n*16 + r16;
        size_t idx = (size_t)grow*3072 + gcol;
        float v = acc[mf][n][reg] + bv[n] + bf2f(resb[idx]);
        out[idx] = f2bf(v);
        s[n] += v; s2[n] += v*v;
      }
    }
  }
  #pragma unroll
  for (int n=0;n<4;n++){
    float a = s[n], b = s2[n];
    a += __shfl_xor(a, 16); a += __shfl_xor(a, 32);
    b += __shfl_xor(b, 16); b += __shfl_xor(b, 32);
    if (quad == 0){
      int col = n0 + wn*64 + n*16 + r16;
      atomicAdd(&stp[col], a);
      atomicAdd(&stp[3072 + col], b);
    }
  }
}

// ---------------- FF2 with fused BN stats ----------------
__global__ __launch_bounds__(256)
void gemm_ff2(const u16* __restrict__ A, const u16* __restrict__ B, const float* __restrict__ bias,
              const u16* __restrict__ resb, u16* __restrict__ out, float* __restrict__ stp)
{
  __shared__ __align__(16) u16 As[128*64];
  __shared__ __align__(16) u16 Bs[128*64];
  int m0 = blockIdx.x*128, n0 = blockIdx.y*128;
  f4 acc[4][4];
  gemm_tile(A + (size_t)m0*256, 256, B + (size_t)n0*256, 256, 256, acc, As, Bs);
  int lane = threadIdx.x & 63, wid = threadIdx.x >> 6;
  int waveM = (wid>>1)*64, waveN = (wid&1)*64;
  int quad = lane>>4, r16 = lane&15;
  float s[4] = {0,0,0,0}, s2[4] = {0,0,0,0};
  #pragma unroll
  for (int mt=0; mt<4; mt++){
    #pragma unroll
    for (int reg=0; reg<4; reg++){
      int grow = m0 + waveM + mt*16 + quad*4 + reg;
      #pragma unroll
      for (int nt=0; nt<4; nt++){
        int gcol = n0 + waveN + nt*16 + r16;
        size_t idx = (size_t)grow*3072 + gcol;
        float v = acc[mt][nt][reg] + bias[gcol] + bf2f(resb[idx]);
        out[idx] = f2bf(v);
        s[nt] += v; s2[nt] += v*v;
      }
    }
  }
  #pragma unroll
  for (int nt=0; nt<4; nt++){
    float a = s[nt], b = s2[nt];
    a += __shfl_xor(a, 16); a += __shfl_xor(a, 32);
    b += __shfl_xor(b, 16); b += __shfl_xor(b, 32);
    if (quad == 0){
      int col = n0 + waveN + nt*16 + r16;
      atomicAdd(&stp[col], a);
      atomicAdd(&stp[3072 + col], b);
    }
  }
}

// FF1: out bf16 = relu(A@B^T + bias)
__global__ __launch_bounds__(256)
void gemm_relu(const u16* __restrict__ A, const u16* __restrict__ B, int K, int N,
               const float* __restrict__ bias, u16* __restrict__ out)
{
  __shared__ __align__(16) u16 As[128*64];
  __shared__ __align__(16) u16 Bs[128*64];
  int m0 = blockIdx.x*128, n0 = blockIdx.y*128;
  f4 acc[4][4];
  gemm_tile(A + (size_t)m0*K, K, B + (size_t)n0*K, K, K, acc, As, Bs);
  int lane = threadIdx.x & 63, wid = threadIdx.x >> 6;
  int waveM = (wid>>1)*64, waveN = (wid&1)*64;
  int quad = lane>>4, r16 = lane&15;
  #pragma unroll
  for (int mt=0; mt<4; mt++){
    #pragma unroll
    for (int reg=0; reg<4; reg++){
      int grow = m0 + waveM + mt*16 + quad*4 + reg;
      #pragma unroll
      for (int nt=0; nt<4; nt++){
        int gcol = n0 + waveN + nt*16 + r16;
        float v = acc[mt][nt][reg] + bias[gcol];
        out[(size_t)grow*N + gcol] = f2bf(v > 0.f ? v : 0.f);
      }
    }
  }
}

// ---------------- merged attention: blocks [0,6144) temporal MFMA, [6144,9984) spatial ----------------
__global__ __launch_bounds__(256)
void attn_both(const u16* __restrict__ qt, const u16* __restrict__ kt,
               const u16* __restrict__ vt, u16* __restrict__ ta,
               const u16* __restrict__ qsp, const u16* __restrict__ ksp,
               const u16* __restrict__ vsp, u16* __restrict__ sa)
{
  __shared__ __align__(16) char smem[39168];
  int tid = threadIdx.x, lane = tid & 63, wid = tid >> 6;
  int quad = lane >> 4, r16 = lane & 15;

  if (blockIdx.x < 6144){
    // ---- temporal: one block per (b,h,j), T=120 pad 128, d=16 pad 32 ----
    u16* P  = (u16*)smem;             // 128*LDP
    u16* Vt = (u16*)(smem + 34816);   // 16*LDP
    int blk = blockIdx.x;
    int b = blk / 192;
    int rem = blk % 192;
    int h = rem / 24, j = rem % 24;
    const u16* qb = qt + (size_t)blk*1920;
    const u16* kb = kt + (size_t)blk*1920;
    const u16* vb = vt + (size_t)blk*1920;

    for (int e = tid; e < 1920; e += 256){
      int s = e >> 4, dd = e & 15;
      Vt[dd*LDP + s] = vb[e];
    }
    if (tid < 128){ int dd = tid >> 3, s = 120 + (tid & 7); Vt[dd*LDP + s] = 0; }
    __syncthreads();

    bf16x8 zv;
    #pragma unroll
    for (int i=0;i<8;i++) zv[i] = (__bf16)0.f;

    const int m0 = wid * 32;
    bf16x8 qf[2];
    #pragma unroll
    for (int mt=0; mt<2; mt++){
      int row = m0 + mt*16 + r16; if (row > 119) row = 119;
      qf[mt] = (quad < 2) ? *(const bf16x8*)&qb[row*16 + (quad&1)*8] : zv;
    }

    f4 S[2][8];
    #pragma unroll
    for (int nt=0; nt<8; nt++){
      int col = nt*16 + r16; int colc = col > 119 ? 119 : col;
      bf16x8 kf = (quad < 2) ? *(const bf16x8*)&kb[colc*16 + (quad&1)*8] : zv;
      #pragma unroll
      for (int mt=0; mt<2; mt++){
        f4 zz = {0.f, 0.f, 0.f, 0.f};
        S[mt][nt] = __builtin_amdgcn_mfma_f32_16x16x32_bf16(qf[mt], kf, zz, 0, 0, 0);
      }
    }

    #pragma unroll
    for (int mt=0; mt<2; mt++)
      #pragma unroll
      for (int nt=0; nt<8; nt++)
        #pragma unroll
        for (int reg=0; reg<4; reg++){
          int c = nt*16 + r16;
          int r = m0 + mt*16 + quad*4 + reg;
          float v = S[mt][nt][reg] * 0.25f;
          S[mt][nt][reg] = (c > r || c >= 120) ? -1e30f : v;
        }

    float Zr[2][4];
    #pragma unroll
    for (int mt=0; mt<2; mt++)
      #pragma unroll
      for (int reg=0; reg<4; reg++){
        float m = -1e30f;
        #pragma unroll
        for (int nt=0; nt<8; nt++) m = fmaxf(m, S[mt][nt][reg]);
        #pragma unroll
        for (int off=1; off<16; off<<=1) m = fmaxf(m, __shfl_xor(m, off, 16));
        float z = 0.f;
        #pragma unroll
        for (int nt=0; nt<8; nt++){
          float e = __expf(S[mt][nt][reg] - m);
          S[mt][nt][reg] = e;
          z += e;
        }
        #pragma unroll
        for (int off=1; off<16; off<<=1) z += __shfl_xor(z, off, 16);
        Zr[mt][reg] = z;
      }

    #pragma unroll
    for (int mt=0; mt<2; mt++)
      #pragma unroll
      for (int nt=0; nt<8; nt++)
        #pragma unroll
        for (int reg=0; reg<4; reg++)
          P[(m0 + mt*16 + quad*4 + reg)*LDP + nt*16 + r16] = f2bf(S[mt][nt][reg]);
    __syncthreads();

    f4 O[2];
    #pragma unroll
    for (int mt=0; mt<2; mt++){ O[mt][0]=0.f; O[mt][1]=0.f; O[mt][2]=0.f; O[mt][3]=0.f; }
    #pragma unroll
    for (int kt8=0; kt8<4; kt8++){
      bf16x8 vf = *(const bf16x8*)&Vt[r16*LDP + kt8*32 + quad*8];
      #pragma unroll
      for (int mt=0; mt<2; mt++){
        bf16x8 pf = *(const bf16x8*)&P[(m0 + mt*16 + r16)*LDP + kt8*32 + quad*8];
        O[mt] = __builtin_amdgcn_mfma_f32_16x16x32_bf16(pf, vf, O[mt], 0, 0, 0);
      }
    }

    #pragma unroll
    for (int mt=0; mt<2; mt++)
      #pragma unroll
      for (int reg=0; reg<4; reg++){
        int r = m0 + mt*16 + quad*4 + reg;
        if (r < 120){
          size_t idx = (size_t)(b*120 + r)*3072 + h*384 + j*16 + r16;
          ta[idx] = f2bf(O[mt][reg] / Zr[mt][reg]);
        }
      }
  } else {
    // ---- spatial: one block per (b,t); threads 0..191 = (h,j); softmax over 24 joints ----
    float* Ks = (float*)smem;            // 3072
    float* Vs = (float*)(smem + 12288);  // 3072
    int bt = blockIdx.x - 6144;
    size_t base = (size_t)bt * 3072;
    for (int c = tid; c < 384; c += 256){
      bf16x8 kv = *(const bf16x8*)&ksp[base + c*8];
      bf16x8 vv = *(const bf16x8*)&vsp[base + c*8];
      #pragma unroll
      for (int i=0;i<8;i++){ Ks[c*8+i] = (float)kv[i]; Vs[c*8+i] = (float)vv[i]; }
    }
    __syncthreads();
    if (tid < 192){
      int h = tid / 24, j = tid % 24;
      float q[16];
      #pragma unroll
      for (int d2=0; d2<16; d2++) q[d2] = bf2f(qsp[base + h*384 + j*16 + d2]);
      float sc[24], mx = -1e30f;
      #pragma unroll
      for (int kk=0; kk<24; kk++){
        float dot = 0.f;
        #pragma unroll
        for (int d2=0; d2<16; d2++) dot += q[d2]*Ks[h*384 + kk*16 + d2];
        sc[kk] = dot * 0.25f;
        mx = fmaxf(mx, sc[kk]);
      }
      float Z = 0.f, acc[16];
      #pragma unroll
      for (int d2=0; d2<16; d2++) acc[d2] = 0.f;
      #pragma unroll
      for (int kk=0; kk<24; kk++){
        float w = __expf(sc[kk] - mx);
        Z += w;
        #pragma unroll
        for (int d2=0; d2<16; d2++) acc[d2] += w*Vs[h*384 + kk*16 + d2];
      }
      float inv = 1.f / Z;
      #pragma unroll
      for (int d2=0; d2<16; d2++) sa[base + h*384 + j*16 + d2] = f2bf(acc[d2]*inv);
    }
  }
}

// ---------------- batchnorm ----------------
// blocks 0..11: temporal coefs; 12..23: spatial coefs
__global__ void bn_coef2(const float* __restrict__ accT, const float* __restrict__ gT,
                         const float* __restrict__ bT, float* __restrict__ cT,
                         const float* __restrict__ accS, const float* __restrict__ gS,
                         const float* __restrict__ bS, float* __restrict__ cS){
  int isS = blockIdx.x >= 12;
  const float* acc = isS ? accS : accT;
  const float* g   = isS ? gS : gT;
  const float* b   = isS ? bS : bT;
  float* coef      = isS ? cS : cT;
  int c = (blockIdx.x % 12)*256 + threadIdx.x;
  float mean = acc[c] * (1.f/3840.f);
  float var  = acc[3072+c] * (1.f/3840.f) - mean*mean;
  float sc = g[c] * rsqrtf(var + 1e-5f);
  coef[c] = sc;
  coef[3072+c] = b[c] - mean*sc;
}

__global__ void bn_coef(const float* __restrict__ acc, const float* __restrict__ g,
                        const float* __restrict__ b, float* __restrict__ coef){
  int c = blockIdx.x*256 + threadIdx.x;
  float mean = acc[c] * (1.f/3840.f);
  float var  = acc[3072+c] * (1.f/3840.f) - mean*mean;
  float sc = g[c] * rsqrtf(var + 1e-5f);
  coef[c] = sc;
  coef[3072+c] = b[c] - mean*sc;
}

// att = BN_t(Yt) + BN_s(Ys), vectorized x4  (channel = (i*4) mod 3072 — NOT a pow2 mask!)
__global__ void bn_apply2(const u16* __restrict__ Ytb, const u16* __restrict__ Ysb,
                          const float* __restrict__ ct, const float* __restrict__ cs,
                          u16* __restrict__ attB){
  int i = blockIdx.x*256 + threadIdx.x;     // < NX/4
  int c = (i*4) % 3072;
  u16x4 yt = *(const u16x4*)&Ytb[i*4];
  u16x4 ys = *(const u16x4*)&Ysb[i*4];
  u16x4 o;
  #pragma unroll
  for (int k=0;k<4;k++){
    float a = bf2f(yt[k])*ct[c+k] + ct[3072+c+k] + bf2f(ys[k])*cs[c+k] + cs[3072+c+k];
    o[k] = f2bf(a);
  }
  *(u16x4*)&attB[i*4] = o;
}

__global__ void bn_out(const u16* __restrict__ Yfb, const float* __restrict__ cf,
                       float* __restrict__ out){
  int i = blockIdx.x*256 + threadIdx.x;     // < NX/4
  int c = (i*4) % 3072;
  u16x4 yf = *(const u16x4*)&Yfb[i*4];
  float4v o;
  #pragma unroll
  for (int k=0;k<4;k++) o[k] = bf2f(yf[k])*cf[c+k] + cf[3072+c+k];
  *(float4v*)&out[i*4] = o;
}

// ---------------- launch ----------------
extern "C" void kernel_launch(void* const* d_in, const int* in_sizes, int n_in,
                              void* d_out, int out_size, void* d_ws, size_t ws_size,
                              hipStream_t stream)
{
  const float* src  = (const float*)d_in[0];
  const float* Wq_t = (const float*)d_in[1];
  const float* Wk_t = (const float*)d_in[2];
  const float* Wv_t = (const float*)d_in[3];
  const float* Wp_t = (const float*)d_in[4];
  const float* bp_t = (const float*)d_in[5];
  const float* g_t  = (const float*)d_in[6];
  const float* b_t  = (const float*)d_in[7];
  const float* Wq_s = (const float*)d_in[8];
  const float* Wk_s = (const float*)d_in[9];
  const float* Wv_s = (const float*)d_in[10];
  const float* Wp_s = (const float*)d_in[11];
  const float* bp_s = (const float*)d_in[12];
  const float* g_s  = (const float*)d_in[13];
  const float* b_s  = (const float*)d_in[14];
  const float* W1   = (const float*)d_in[15];
  const float* b1   = (const float*)d_in[16];
  const float* W2   = (const float*)d_in[17];
  const float* b2   = (const float*)d_in[18];
  const float* g_f  = (const float*)d_in[19];
  const float* b_f  = (const float*)d_in[20];

  char* ws = (char*)d_ws;
  u16* x_bf  = (u16*)(ws + 0ull);
  u16* wptb  = (u16*)(ws + 23592960ull);
  u16* wpsb  = (u16*)(ws + 42467328ull);
  u16* w1b   = (u16*)(ws + 61341696ull);
  u16* w2b   = (u16*)(ws + 62914560ull);
  u16* wcat  = (u16*)(ws + 64487424ull);
  u16* qt    = (u16*)(ws + 69206016ull);
  u16* kt    = qt + NX;
  u16* vt    = kt + NX;
  u16* qs    = vt + NX;
  u16* ks    = qs + NX;
  u16* vs    = ks + NX;
  u16* tab   = (u16*)(ws + 210763776ull);
  u16* sab   = (u16*)(ws + 234356736ull);
  float* accT = (float*)(ws + 257949696ull);
  float* accS = accT + 6144;
  float* accF = accS + 6144;
  float* cT   = accF + 6144;
  float* cS   = cT + 6144;
  float* cF   = cS + 6144;
  // bf16 aliases over dead regions
  u16* Ytb  = qt;   // dead after attention
  u16* Ysb  = kt;
  u16* attB = vt;
  u16* Yfb  = qs;
  u16* h1   = wcat; // dead after gemm_qkv
  float* out = (float*)d_out;

  // 1. fused prep (zero accs + conversions + weight pack)
  k_prep<<<40776, 256, 0, stream>>>(src, x_bf, Wp_t, wptb, Wp_s, wpsb, W1, w1b, W2, w2b,
                                    Wq_t, Wk_t, Wv_t, Wq_s, Wk_s, Wv_s, wcat, accT);
  // 2. QKV projections (per joint; A staged once, 6 B-chunks)
  gemm_qkv<<<dim3(30,24), 256, 0, stream>>>(x_bf, wcat, qt, kt, vt, qs, ks, vs);
  // 3. both attentions in one launch
  attn_both<<<9984, 256, 0, stream>>>(qt, kt, vt, tab, qs, ks, vs, sab);
  // 4. output projections + residual + fused BN stats (reduced-lockstep 8-phase)
  gemm_proj8<<<dim3(15,12,2), 512, 0, stream>>>(tab, wptb, bp_t, sab, wpsb, bp_s,
                                                x_bf, Ytb, Ysb, accT, accS);
  // 5. BN coefs (t+s) + fused apply
  bn_coef2<<<24, 256, 0, stream>>>(accT, g_t, b_t, cT, accS, g_s, b_s, cS);
  bn_apply2<<<11520, 256, 0, stream>>>(Ytb, Ysb, cT, cS, attB);
  // 6. feed-forward
  gemm_relu<<<dim3(30,2), 256, 0, stream>>>(attB, w1b, 3072, 256, b1, h1);
  gemm_ff2<<<dim3(30,24), 256, 0, stream>>>(h1, w2b, b2, attB, Yfb, accF);
  // 7. final BN
  bn_coef<<<12, 256, 0, stream>>>(accF, g_f, b_f, cF);
  bn_out<<<11520, 256, 0, stream>>>(Yfb, cF, out);
}

// Round 3
// 603.965 us; speedup vs baseline: 1.1696x; 1.0942x over previous
//
#include <hip/hip_runtime.h>

typedef unsigned short u16;
typedef __bf16 bf16x8 __attribute__((ext_vector_type(8)));
typedef float f4 __attribute__((ext_vector_type(4)));
typedef float float4v __attribute__((ext_vector_type(4)));
typedef u16 u16x4 __attribute__((ext_vector_type(4)));

#define NX 11796480   // B*T*D = 3840*3072
#define LDP 136       // padded LDS row (u16 elems) for P / Vt in temporal attn

__device__ __forceinline__ float bf2f(u16 u){ __bf16 h = __builtin_bit_cast(__bf16, u); return (float)h; }
__device__ __forceinline__ u16 f2bf(float f){ __bf16 h = (__bf16)f; return __builtin_bit_cast(u16, h); }

__device__ __forceinline__ void gload_lds16(const u16* g, u16* l){
  __builtin_amdgcn_global_load_lds((const __attribute__((address_space(1))) void*)g,
                                   (__attribute__((address_space(3))) void*)l, 16, 0, 0);
}

// ---------------- fused prep: zero BN accs + all fp32->bf16 conversions + QKV weight pack ----------------
__device__ __forceinline__ void cvt4seg(const float* __restrict__ in, u16* __restrict__ out, int i){
  float4v v = *(const float4v*)&in[i*4];
  u16x4 o;
  o[0]=f2bf(v[0]); o[1]=f2bf(v[1]); o[2]=f2bf(v[2]); o[3]=f2bf(v[3]);
  *(u16x4*)&out[i*4] = o;
}

// total items = 18432 + 2949120 + 2359296 + 2359296 + 196608 + 196608 + 2359296 = 10438656 = 40776*256
__global__ void k_prep(const float* __restrict__ src, u16* __restrict__ x_bf,
                       const float* __restrict__ wpt, u16* __restrict__ wptb,
                       const float* __restrict__ wps, u16* __restrict__ wpsb,
                       const float* __restrict__ w1,  u16* __restrict__ w1b,
                       const float* __restrict__ w2,  u16* __restrict__ w2b,
                       const float* __restrict__ wqt, const float* __restrict__ wkt,
                       const float* __restrict__ wvt, const float* __restrict__ wqs,
                       const float* __restrict__ wks, const float* __restrict__ wvs,
                       u16* __restrict__ wcat, float* __restrict__ accs){
  int i = blockIdx.x*256 + threadIdx.x;
  if (i < 18432){ accs[i] = 0.f; return; }
  i -= 18432;
  if (i < 2949120){ cvt4seg(src, x_bf, i); return; }
  i -= 2949120;
  if (i < 2359296){ cvt4seg(wpt, wptb, i); return; }
  i -= 2359296;
  if (i < 2359296){ cvt4seg(wps, wpsb, i); return; }
  i -= 2359296;
  if (i < 196608){ cvt4seg(w1, w1b, i); return; }
  i -= 196608;
  if (i < 196608){ cvt4seg(w2, w2b, i); return; }
  i -= 196608;
  // pack Wq_t|Wk_t|Wv_t|Wq_s|Wk_s|Wv_s into (J=24, N=768, K=128) row-major bf16
  int e = i & 127;
  int n = (i >> 7) % 768;
  int j = i / (768*128);
  float v;
  if (n < 512){
    int tn = n >> 7, hh = (n >> 4) & 7, dd = n & 15;
    const float* W = (tn==0)? wqt : (tn==1)? wkt : (tn==2)? wvt : wqs;  // (H,J,d,E)
    v = W[(((hh*24 + j)*16 + dd) << 7) + e];
  } else {
    int m = n - 512;
    int tn = m >> 7, hh = (m >> 4) & 7, dd = m & 15;
    const float* W = (tn==0)? wks : wvs;                                // (H,d,E)
    v = W[((hh*16 + dd) << 7) + e];
  }
  wcat[i] = f2bf(v);
}

// ---------------- MFMA GEMM core (BK=64): C[128,128] tile of A[M,K]*B[N,K]^T ----------------
// (kept for gemm_relu / gemm_ff2 — small-K GEMMs)
__device__ __forceinline__ void gemm_tile(const u16* __restrict__ Ab, int lda,
                                          const u16* __restrict__ Bb, int ldb,
                                          int K, f4 acc[4][4], u16* As, u16* Bs)
{
  const int tid  = threadIdx.x;
  const int lane = tid & 63;
  const int wid  = tid >> 6;
  const int waveM = (wid >> 1) * 64;
  const int waveN = (wid & 1) * 64;
  const int quad = lane >> 4;
  const int r16  = lane & 15;
  const int srow = tid >> 3;                       // 0..31
  const int gcol = ((tid & 7) ^ (srow & 7)) * 8;   // swizzled source column

  #pragma unroll
  for (int mt=0; mt<4; mt++)
    #pragma unroll
    for (int nt=0; nt<4; nt++)
      #pragma unroll
      for (int q=0; q<4; q++) acc[mt][nt][q] = 0.f;

  for (int k0 = 0; k0 < K; k0 += 64){
    __syncthreads();
    #pragma unroll
    for (int i=0; i<4; i++){
      int row = srow + i*32;
      gload_lds16(&Ab[(size_t)row*lda + k0 + gcol], As + wid*512 + i*2048);
      gload_lds16(&Bb[(size_t)row*ldb + k0 + gcol], Bs + wid*512 + i*2048);
    }
    __builtin_amdgcn_s_waitcnt(0);
    __syncthreads();
    #pragma unroll
    for (int kk=0; kk<2; kk++){
      bf16x8 af[4], bfr[4];
      const int soff = ((kk*4 + quad) ^ (r16 & 7)) * 8;   // swizzled read slot
      #pragma unroll
      for (int mt=0; mt<4; mt++)
        af[mt] = *(const bf16x8*)&As[(waveM + mt*16 + r16)*64 + soff];
      #pragma unroll
      for (int nt=0; nt<4; nt++)
        bfr[nt] = *(const bf16x8*)&Bs[(waveN + nt*16 + r16)*64 + soff];
      #pragma unroll
      for (int mt=0; mt<4; mt++)
        #pragma unroll
        for (int nt=0; nt<4; nt++)
          acc[mt][nt] = __builtin_amdgcn_mfma_f32_16x16x32_bf16(af[mt], bfr[nt], acc[mt][nt], 0, 0, 0);
    }
  }
  __syncthreads();
}

// ---------------- QKV GEMM: stage A once, loop 6 B-chunks of 128 (N=768 total) ----------------
__global__ __launch_bounds__(256)
void gemm_qkv(const u16* __restrict__ x, const u16* __restrict__ wcat,
              u16* __restrict__ qt, u16* __restrict__ kt, u16* __restrict__ vt,
              u16* __restrict__ qs, u16* __restrict__ ks, u16* __restrict__ vs)
{
  __shared__ __align__(16) u16 As[128*128];
  __shared__ __align__(16) u16 Bs[128*128];
  int m0 = blockIdx.x*128, j = blockIdx.y;
  const u16* Ab = x + (size_t)m0*3072 + j*128;
  const u16* Bbase = wcat + (size_t)j*98304;
  int tid = threadIdx.x, lane = tid & 63, wid = tid >> 6;
  int quad = lane >> 4, r16 = lane & 15;
  int srow16 = tid >> 4;                   // 0..15
  int cslot  = tid & 15;
  int gcol   = (cslot ^ srow16) * 8;       // swizzled source column

  #pragma unroll
  for (int it=0; it<8; it++){
    int row = srow16 + it*16;
    gload_lds16(&Ab[(size_t)row*3072 + gcol], As + tid*8 + it*2048);
  }

  int waveM = (wid>>1)*64, waveN = (wid&1)*64;

  for (int nc=0; nc<6; nc++){
    const u16* Bb = Bbase + (size_t)(nc*128)*128;
    #pragma unroll
    for (int it=0; it<8; it++){
      int row = srow16 + it*16;
      gload_lds16(&Bb[(size_t)row*128 + gcol], Bs + tid*8 + it*2048);
    }
    __builtin_amdgcn_s_waitcnt(0);
    __syncthreads();

    f4 acc[4][4];
    #pragma unroll
    for (int mt=0; mt<4; mt++)
      #pragma unroll
      for (int nt=0; nt<4; nt++)
        #pragma unroll
        for (int q=0; q<4; q++) acc[mt][nt][q] = 0.f;

    #pragma unroll
    for (int kk=0; kk<4; kk++){
      bf16x8 af[4], bfr[4];
      const int soff = ((kk*4 + quad) ^ r16) * 8;
      #pragma unroll
      for (int mt=0; mt<4; mt++)
        af[mt] = *(const bf16x8*)&As[(waveM + mt*16 + r16)*128 + soff];
      #pragma unroll
      for (int nt=0; nt<4; nt++)
        bfr[nt] = *(const bf16x8*)&Bs[(waveN + nt*16 + r16)*128 + soff];
      #pragma unroll
      for (int mt=0; mt<4; mt++)
        #pragma unroll
        for (int nt=0; nt<4; nt++)
          acc[mt][nt] = __builtin_amdgcn_mfma_f32_16x16x32_bf16(af[mt], bfr[nt], acc[mt][nt], 0, 0, 0);
    }

    #pragma unroll
    for (int mt=0; mt<4; mt++){
      #pragma unroll
      for (int reg=0; reg<4; reg++){
        int row = m0 + waveM + mt*16 + quad*4 + reg;   // bt index
        int b = row / 120, t = row % 120;
        #pragma unroll
        for (int nt=0; nt<4; nt++){
          int n = nc*128 + waveN + nt*16 + r16;
          u16 uv = f2bf(acc[mt][nt][reg]);
          if (n < 384){
            int tn = n >> 7, hh = (n >> 4) & 7, dd = n & 15;
            u16* base = (tn==0)? qt : (tn==1)? kt : vt;
            base[((((size_t)(b*8+hh)*24 + j)*120 + t) << 4) + dd] = uv;
          } else {
            int m2 = n - 384;
            int tn = m2 >> 7, hh = (m2 >> 4) & 7, dd = m2 & 15;
            u16* base = (tn==0)? qs : (tn==1)? ks : vs;
            base[((((size_t)row*8 + hh)*24 + j) << 4) + dd] = uv;
          }
        }
      }
    }
    __syncthreads();   // all waves done reading Bs before next chunk restages
  }
}

// ================= 256x384 dual-projection GEMM, BK=32, 3-slot rotating LDS =================
// Grid 15 x 8 x 2 = 240 blocks = ONE full round on 256 CUs (no tail).
// 512 threads = 8 waves (2M x 4N); per-wave output 128x96 (8 m-frags x 6 n-frags).
// LDS: 3 slots x { A[256][32] (16 KB) | B[384][32] (24 KB) } = 120 KiB.
// Ledger (per K-tile, verified): tile t reads slot t%3; stages A(t+2),B(t+2) into slot
// (t+2)%3 whose previous contents (tile t-1) were consumed before the barrier ending t-1;
// vmcnt(5) at end of t retires all but the newest A+B (=tile t+2's 5 issues), publishing
// tile t+1. ONE barrier + ONE vmcnt per K-tile; never vmcnt(0) in the loop.
// XCD chunk swizzle (bijective, 240%8==0): XCD k owns 30 consecutive tiles = 2 full
// x-columns sharing 2 B-panels (4.5 MB ~ L2) -> B reused 15x from L2.

__device__ __forceinline__ void stageA384(const u16* __restrict__ g, int kcol,
                                          u16* __restrict__ slotA, int lane, int wid){
  #pragma unroll
  for (int i=0;i<2;i++){
    int row = wid*32 + i*16 + (lane>>2);
    int sw  = (((lane & 3) ^ ((lane>>3) & 3)) << 3);   // inverse of read swizzle
    gload_lds16(&g[(size_t)row*3072 + kcol + sw], slotA + (wid*2+i)*512);
  }
}
__device__ __forceinline__ void stageB384(const u16* __restrict__ g, int kcol,
                                          u16* __restrict__ slotB, int lane, int wid){
  #pragma unroll
  for (int i=0;i<3;i++){
    int row = wid*48 + i*16 + (lane>>2);
    int sw  = (((lane & 3) ^ ((lane>>3) & 3)) << 3);
    gload_lds16(&g[(size_t)row*3072 + kcol + sw], slotB + (wid*3+i)*512);
  }
}

__global__ __launch_bounds__(512, 2)
void gemm_proj384(const u16* __restrict__ A0, const u16* __restrict__ B0, const float* __restrict__ b0,
                  const u16* __restrict__ A1, const u16* __restrict__ B1, const float* __restrict__ b1v,
                  const u16* __restrict__ resb, u16* __restrict__ O0, u16* __restrict__ O1,
                  float* __restrict__ st0, float* __restrict__ st1)
{
  __shared__ __align__(16) u16 smem[61440];     // 120 KiB = 3 slots x 20480 u16
  const int tid = threadIdx.x, lane = tid & 63, wid = tid >> 6;
  const int quad = lane >> 4, r16 = lane & 15;
  const int wm = wid >> 2, wn = wid & 3;

  // bijective XCD chunk swizzle over 240 blocks
  int lin = blockIdx.x + 15*blockIdx.y + 120*blockIdx.z;
  int nidx = (lin & 7)*30 + (lin >> 3);
  int zz = nidx / 120; int rem = nidx - zz*120;
  int by = rem / 15, bx = rem - by*15;

  const int m0 = bx*256, n0 = by*384;
  const u16* Ag = (zz ? A1 : A0) + (size_t)m0*3072;
  const u16* Bg = (zz ? B1 : B0) + (size_t)n0*3072;
  const float* bias = zz ? b1v : b0;
  u16* out = zz ? O1 : O0;
  float* stp = zz ? st1 : st0;

  const int soff = ((quad ^ ((r16>>1)&3)) << 3);
  const int arow = wm*128 + r16;
  const int brow = wn*96 + r16;

  f4 acc[8][6];
  #pragma unroll
  for (int i=0;i<8;i++)
    #pragma unroll
    for (int n=0;n<6;n++)
      #pragma unroll
      for (int q=0;q<4;q++) acc[i][n][q] = 0.f;

  u16* Sa = smem;            // slot holding tile t
  u16* Sb = smem + 20480;    // tile t+1
  u16* Sc = smem + 40960;    // tile t+2 (stage target)

  // prologue: tiles 0 and 1 (10 issues/wave)
  stageA384(Ag, 0,  Sa,        lane, wid);
  stageB384(Bg, 0,  Sa + 8192, lane, wid);
  stageA384(Ag, 32, Sb,        lane, wid);
  stageB384(Bg, 32, Sb + 8192, lane, wid);
  asm volatile("s_waitcnt vmcnt(5)" ::: "memory");   // tile 0 landed
  __builtin_amdgcn_s_barrier();

  const int NT = 96;                                 // K = 3072, BK = 32
  bf16x8 af[4], bf[6];

  for (int t=0; t<NT; ++t){
    const int kc2 = ((t+2 < NT) ? (t+2) : 0) * 32;   // clamped tail lands in dead slot

    // ---- p0: m-group 0 + all B frags; stage A(t+2) ----
    #pragma unroll
    for (int i=0;i<4;i++) af[i] = *(const bf16x8*)&Sa[(arow + i*16)*32 + soff];
    #pragma unroll
    for (int n=0;n<6;n++) bf[n] = *(const bf16x8*)&Sa[8192 + (brow + n*16)*32 + soff];
    stageA384(Ag, kc2, Sc, lane, wid);
    __builtin_amdgcn_s_setprio(1);
    #pragma unroll
    for (int i=0;i<4;i++)
      #pragma unroll
      for (int n=0;n<6;n++)
        acc[i][n] = __builtin_amdgcn_mfma_f32_16x16x32_bf16(af[i], bf[n], acc[i][n], 0,0,0);
    __builtin_amdgcn_s_setprio(0);

    // ---- p1: m-group 1 (reuse bf); stage B(t+2) ----
    #pragma unroll
    for (int i=0;i<4;i++) af[i] = *(const bf16x8*)&Sa[(arow + 64 + i*16)*32 + soff];
    stageB384(Bg, kc2, Sc + 8192, lane, wid);
    __builtin_amdgcn_s_setprio(1);
    #pragma unroll
    for (int i=0;i<4;i++)
      #pragma unroll
      for (int n=0;n<6;n++)
        acc[4+i][n] = __builtin_amdgcn_mfma_f32_16x16x32_bf16(af[i], bf[n], acc[4+i][n], 0,0,0);
    __builtin_amdgcn_s_setprio(0);

    asm volatile("s_waitcnt vmcnt(5)" ::: "memory"); // tile t+1 published
    __builtin_amdgcn_s_barrier();
    u16* tp = Sa; Sa = Sb; Sb = Sc; Sc = tp;         // rotate slots
  }
  asm volatile("s_waitcnt vmcnt(0)" ::: "memory");   // drain clamped tail DMAs

  // ---------- epilogue: bias + residual + bf16 store + fused BN stats ----------
  float bv[6];
  #pragma unroll
  for (int n=0;n<6;n++) bv[n] = bias[n0 + wn*96 + n*16 + r16];
  float s[6] = {0,0,0,0,0,0}, s2[6] = {0,0,0,0,0,0};
  #pragma unroll
  for (int mf=0; mf<8; mf++){
    #pragma unroll
    for (int reg=0; reg<4; reg++){
      int grow = m0 + wm*128 + mf*16 + quad*4 + reg;
      #pragma unroll
      for (int n=0;n<6;n++){
        int gcol = n0 + wn*96 + n*16 + r16;
        size_t idx = (size_t)grow*3072 + gcol;
        float v = acc[mf][n][reg] + bv[n] + bf2f(resb[idx]);
        out[idx] = f2bf(v);
        s[n] += v; s2[n] += v*v;
      }
    }
  }
  #pragma unroll
  for (int n=0;n<6;n++){
    float a = s[n], b = s2[n];
    a += __shfl_xor(a, 16); a += __shfl_xor(a, 32);
    b += __shfl_xor(b, 16); b += __shfl_xor(b, 32);
    if (quad == 0){
      int col = n0 + wn*96 + n*16 + r16;
      atomicAdd(&stp[col], a);
      atomicAdd(&stp[3072 + col], b);
    }
  }
}

// ---------------- FF2 with fused BN stats ----------------
__global__ __launch_bounds__(256)
void gemm_ff2(const u16* __restrict__ A, const u16* __restrict__ B, const float* __restrict__ bias,
              const u16* __restrict__ resb, u16* __restrict__ out, float* __restrict__ stp)
{
  __shared__ __align__(16) u16 As[128*64];
  __shared__ __align__(16) u16 Bs[128*64];
  int m0 = blockIdx.x*128, n0 = blockIdx.y*128;
  f4 acc[4][4];
  gemm_tile(A + (size_t)m0*256, 256, B + (size_t)n0*256, 256, 256, acc, As, Bs);
  int lane = threadIdx.x & 63, wid = threadIdx.x >> 6;
  int waveM = (wid>>1)*64, waveN = (wid&1)*64;
  int quad = lane>>4, r16 = lane&15;
  float s[4] = {0,0,0,0}, s2[4] = {0,0,0,0};
  #pragma unroll
  for (int mt=0; mt<4; mt++){
    #pragma unroll
    for (int reg=0; reg<4; reg++){
      int grow = m0 + waveM + mt*16 + quad*4 + reg;
      #pragma unroll
      for (int nt=0; nt<4; nt++){
        int gcol = n0 + waveN + nt*16 + r16;
        size_t idx = (size_t)grow*3072 + gcol;
        float v = acc[mt][nt][reg] + bias[gcol] + bf2f(resb[idx]);
        out[idx] = f2bf(v);
        s[nt] += v; s2[nt] += v*v;
      }
    }
  }
  #pragma unroll
  for (int nt=0; nt<4; nt++){
    float a = s[nt], b = s2[nt];
    a += __shfl_xor(a, 16); a += __shfl_xor(a, 32);
    b += __shfl_xor(b, 16); b += __shfl_xor(b, 32);
    if (quad == 0){
      int col = n0 + waveN + nt*16 + r16;
      atomicAdd(&stp[col], a);
      atomicAdd(&stp[3072 + col], b);
    }
  }
}

// FF1: out bf16 = relu(A@B^T + bias)
__global__ __launch_bounds__(256)
void gemm_relu(const u16* __restrict__ A, const u16* __restrict__ B, int K, int N,
               const float* __restrict__ bias, u16* __restrict__ out)
{
  __shared__ __align__(16) u16 As[128*64];
  __shared__ __align__(16) u16 Bs[128*64];
  int m0 = blockIdx.x*128, n0 = blockIdx.y*128;
  f4 acc[4][4];
  gemm_tile(A + (size_t)m0*K, K, B + (size_t)n0*K, K, K, acc, As, Bs);
  int lane = threadIdx.x & 63, wid = threadIdx.x >> 6;
  int waveM = (wid>>1)*64, waveN = (wid&1)*64;
  int quad = lane>>4, r16 = lane&15;
  #pragma unroll
  for (int mt=0; mt<4; mt++){
    #pragma unroll
    for (int reg=0; reg<4; reg++){
      int grow = m0 + waveM + mt*16 + quad*4 + reg;
      #pragma unroll
      for (int nt=0; nt<4; nt++){
        int gcol = n0 + waveN + nt*16 + r16;
        float v = acc[mt][nt][reg] + bias[gcol];
        out[(size_t)grow*N + gcol] = f2bf(v > 0.f ? v : 0.f);
      }
    }
  }
}

// ---------------- merged attention: blocks [0,6144) temporal MFMA, [6144,9984) spatial ----------------
__global__ __launch_bounds__(256)
void attn_both(const u16* __restrict__ qt, const u16* __restrict__ kt,
               const u16* __restrict__ vt, u16* __restrict__ ta,
               const u16* __restrict__ qsp, const u16* __restrict__ ksp,
               const u16* __restrict__ vsp, u16* __restrict__ sa)
{
  __shared__ __align__(16) char smem[39168];
  int tid = threadIdx.x, lane = tid & 63, wid = tid >> 6;
  int quad = lane >> 4, r16 = lane & 15;

  if (blockIdx.x < 6144){
    // ---- temporal: one block per (b,h,j), T=120 pad 128, d=16 pad 32 ----
    u16* P  = (u16*)smem;             // 128*LDP
    u16* Vt = (u16*)(smem + 34816);   // 16*LDP
    int blk = blockIdx.x;
    int b = blk / 192;
    int rem = blk % 192;
    int h = rem / 24, j = rem % 24;
    const u16* qb = qt + (size_t)blk*1920;
    const u16* kb = kt + (size_t)blk*1920;
    const u16* vb = vt + (size_t)blk*1920;

    for (int e = tid; e < 1920; e += 256){
      int s = e >> 4, dd = e & 15;
      Vt[dd*LDP + s] = vb[e];
    }
    if (tid < 128){ int dd = tid >> 3, s = 120 + (tid & 7); Vt[dd*LDP + s] = 0; }
    __syncthreads();

    bf16x8 zv;
    #pragma unroll
    for (int i=0;i<8;i++) zv[i] = (__bf16)0.f;

    const int m0 = wid * 32;
    bf16x8 qf[2];
    #pragma unroll
    for (int mt=0; mt<2; mt++){
      int row = m0 + mt*16 + r16; if (row > 119) row = 119;
      qf[mt] = (quad < 2) ? *(const bf16x8*)&qb[row*16 + (quad&1)*8] : zv;
    }

    f4 S[2][8];
    #pragma unroll
    for (int nt=0; nt<8; nt++){
      int col = nt*16 + r16; int colc = col > 119 ? 119 : col;
      bf16x8 kf = (quad < 2) ? *(const bf16x8*)&kb[colc*16 + (quad&1)*8] : zv;
      #pragma unroll
      for (int mt=0; mt<2; mt++){
        f4 zz = {0.f, 0.f, 0.f, 0.f};
        S[mt][nt] = __builtin_amdgcn_mfma_f32_16x16x32_bf16(qf[mt], kf, zz, 0, 0, 0);
      }
    }

    #pragma unroll
    for (int mt=0; mt<2; mt++)
      #pragma unroll
      for (int nt=0; nt<8; nt++)
        #pragma unroll
        for (int reg=0; reg<4; reg++){
          int c = nt*16 + r16;
          int r = m0 + mt*16 + quad*4 + reg;
          float v = S[mt][nt][reg] * 0.25f;
          S[mt][nt][reg] = (c > r || c >= 120) ? -1e30f : v;
        }

    float Zr[2][4];
    #pragma unroll
    for (int mt=0; mt<2; mt++)
      #pragma unroll
      for (int reg=0; reg<4; reg++){
        float m = -1e30f;
        #pragma unroll
        for (int nt=0; nt<8; nt++) m = fmaxf(m, S[mt][nt][reg]);
        #pragma unroll
        for (int off=1; off<16; off<<=1) m = fmaxf(m, __shfl_xor(m, off, 16));
        float z = 0.f;
        #pragma unroll
        for (int nt=0; nt<8; nt++){
          float e = __expf(S[mt][nt][reg] - m);
          S[mt][nt][reg] = e;
          z += e;
        }
        #pragma unroll
        for (int off=1; off<16; off<<=1) z += __shfl_xor(z, off, 16);
        Zr[mt][reg] = z;
      }

    #pragma unroll
    for (int mt=0; mt<2; mt++)
      #pragma unroll
      for (int nt=0; nt<8; nt++)
        #pragma unroll
        for (int reg=0; reg<4; reg++)
          P[(m0 + mt*16 + quad*4 + reg)*LDP + nt*16 + r16] = f2bf(S[mt][nt][reg]);
    __syncthreads();

    f4 O[2];
    #pragma unroll
    for (int mt=0; mt<2; mt++){ O[mt][0]=0.f; O[mt][1]=0.f; O[mt][2]=0.f; O[mt][3]=0.f; }
    #pragma unroll
    for (int kt8=0; kt8<4; kt8++){
      bf16x8 vf = *(const bf16x8*)&Vt[r16*LDP + kt8*32 + quad*8];
      #pragma unroll
      for (int mt=0; mt<2; mt++){
        bf16x8 pf = *(const bf16x8*)&P[(m0 + mt*16 + r16)*LDP + kt8*32 + quad*8];
        O[mt] = __builtin_amdgcn_mfma_f32_16x16x32_bf16(pf, vf, O[mt], 0, 0, 0);
      }
    }

    #pragma unroll
    for (int mt=0; mt<2; mt++)
      #pragma unroll
      for (int reg=0; reg<4; reg++){
        int r = m0 + mt*16 + quad*4 + reg;
        if (r < 120){
          size_t idx = (size_t)(b*120 + r)*3072 + h*384 + j*16 + r16;
          ta[idx] = f2bf(O[mt][reg] / Zr[mt][reg]);
        }
      }
  } else {
    // ---- spatial: one block per (b,t); threads 0..191 = (h,j); softmax over 24 joints ----
    float* Ks = (float*)smem;            // 3072
    float* Vs = (float*)(smem + 12288);  // 3072
    int bt = blockIdx.x - 6144;
    size_t base = (size_t)bt * 3072;
    for (int c = tid; c < 384; c += 256){
      bf16x8 kv = *(const bf16x8*)&ksp[base + c*8];
      bf16x8 vv = *(const bf16x8*)&vsp[base + c*8];
      #pragma unroll
      for (int i=0;i<8;i++){ Ks[c*8+i] = (float)kv[i]; Vs[c*8+i] = (float)vv[i]; }
    }
    __syncthreads();
    if (tid < 192){
      int h = tid / 24, j = tid % 24;
      float q[16];
      #pragma unroll
      for (int d2=0; d2<16; d2++) q[d2] = bf2f(qsp[base + h*384 + j*16 + d2]);
      float sc[24], mx = -1e30f;
      #pragma unroll
      for (int kk=0; kk<24; kk++){
        float dot = 0.f;
        #pragma unroll
        for (int d2=0; d2<16; d2++) dot += q[d2]*Ks[h*384 + kk*16 + d2];
        sc[kk] = dot * 0.25f;
        mx = fmaxf(mx, sc[kk]);
      }
      float Z = 0.f, acc[16];
      #pragma unroll
      for (int d2=0; d2<16; d2++) acc[d2] = 0.f;
      #pragma unroll
      for (int kk=0; kk<24; kk++){
        float w = __expf(sc[kk] - mx);
        Z += w;
        #pragma unroll
        for (int d2=0; d2<16; d2++) acc[d2] += w*Vs[h*384 + kk*16 + d2];
      }
      float inv = 1.f / Z;
      #pragma unroll
      for (int d2=0; d2<16; d2++) sa[base + h*384 + j*16 + d2] = f2bf(acc[d2]*inv);
    }
  }
}

// ---------------- batchnorm ----------------
// blocks 0..11: temporal coefs; 12..23: spatial coefs
__global__ void bn_coef2(const float* __restrict__ accT, const float* __restrict__ gT,
                         const float* __restrict__ bT, float* __restrict__ cT,
                         const float* __restrict__ accS, const float* __restrict__ gS,
                         const float* __restrict__ bS, float* __restrict__ cS){
  int isS = blockIdx.x >= 12;
  const float* acc = isS ? accS : accT;
  const float* g   = isS ? gS : gT;
  const float* b   = isS ? bS : bT;
  float* coef      = isS ? cS : cT;
  int c = (blockIdx.x % 12)*256 + threadIdx.x;
  float mean = acc[c] * (1.f/3840.f);
  float var  = acc[3072+c] * (1.f/3840.f) - mean*mean;
  float sc = g[c] * rsqrtf(var + 1e-5f);
  coef[c] = sc;
  coef[3072+c] = b[c] - mean*sc;
}

__global__ void bn_coef(const float* __restrict__ acc, const float* __restrict__ g,
                        const float* __restrict__ b, float* __restrict__ coef){
  int c = blockIdx.x*256 + threadIdx.x;
  float mean = acc[c] * (1.f/3840.f);
  float var  = acc[3072+c] * (1.f/3840.f) - mean*mean;
  float sc = g[c] * rsqrtf(var + 1e-5f);
  coef[c] = sc;
  coef[3072+c] = b[c] - mean*sc;
}

// att = BN_t(Yt) + BN_s(Ys), vectorized x4  (channel = (i*4) mod 3072 — NOT a pow2 mask!)
__global__ void bn_apply2(const u16* __restrict__ Ytb, const u16* __restrict__ Ysb,
                          const float* __restrict__ ct, const float* __restrict__ cs,
                          u16* __restrict__ attB){
  int i = blockIdx.x*256 + threadIdx.x;     // < NX/4
  int c = (i*4) % 3072;
  u16x4 yt = *(const u16x4*)&Ytb[i*4];
  u16x4 ys = *(const u16x4*)&Ysb[i*4];
  u16x4 o;
  #pragma unroll
  for (int k=0;k<4;k++){
    float a = bf2f(yt[k])*ct[c+k] + ct[3072+c+k] + bf2f(ys[k])*cs[c+k] + cs[3072+c+k];
    o[k] = f2bf(a);
  }
  *(u16x4*)&attB[i*4] = o;
}

__global__ void bn_out(const u16* __restrict__ Yfb, const float* __restrict__ cf,
                       float* __restrict__ out){
  int i = blockIdx.x*256 + threadIdx.x;     // < NX/4
  int c = (i*4) % 3072;
  u16x4 yf = *(const u16x4*)&Yfb[i*4];
  float4v o;
  #pragma unroll
  for (int k=0;k<4;k++) o[k] = bf2f(yf[k])*cf[c+k] + cf[3072+c+k];
  *(float4v*)&out[i*4] = o;
}

// ---------------- launch ----------------
extern "C" void kernel_launch(void* const* d_in, const int* in_sizes, int n_in,
                              void* d_out, int out_size, void* d_ws, size_t ws_size,
                              hipStream_t stream)
{
  const float* src  = (const float*)d_in[0];
  const float* Wq_t = (const float*)d_in[1];
  const float* Wk_t = (const float*)d_in[2];
  const float* Wv_t = (const float*)d_in[3];
  const float* Wp_t = (const float*)d_in[4];
  const float* bp_t = (const float*)d_in[5];
  const float* g_t  = (const float*)d_in[6];
  const float* b_t  = (const float*)d_in[7];
  const float* Wq_s = (const float*)d_in[8];
  const float* Wk_s = (const float*)d_in[9];
  const float* Wv_s = (const float*)d_in[10];
  const float* Wp_s = (const float*)d_in[11];
  const float* bp_s = (const float*)d_in[12];
  const float* g_s  = (const float*)d_in[13];
  const float* b_s  = (const float*)d_in[14];
  const float* W1   = (const float*)d_in[15];
  const float* b1   = (const float*)d_in[16];
  const float* W2   = (const float*)d_in[17];
  const float* b2   = (const float*)d_in[18];
  const float* g_f  = (const float*)d_in[19];
  const float* b_f  = (const float*)d_in[20];

  char* ws = (char*)d_ws;
  u16* x_bf  = (u16*)(ws + 0ull);
  u16* wptb  = (u16*)(ws + 23592960ull);
  u16* wpsb  = (u16*)(ws + 42467328ull);
  u16* w1b   = (u16*)(ws + 61341696ull);
  u16* w2b   = (u16*)(ws + 62914560ull);
  u16* wcat  = (u16*)(ws + 64487424ull);
  u16* qt    = (u16*)(ws + 69206016ull);
  u16* kt    = qt + NX;
  u16* vt    = kt + NX;
  u16* qs    = vt + NX;
  u16* ks    = qs + NX;
  u16* vs    = ks + NX;
  u16* tab   = (u16*)(ws + 210763776ull);
  u16* sab   = (u16*)(ws + 234356736ull);
  float* accT = (float*)(ws + 257949696ull);
  float* accS = accT + 6144;
  float* accF = accS + 6144;
  float* cT   = accF + 6144;
  float* cS   = cT + 6144;
  float* cF   = cS + 6144;
  // bf16 aliases over dead regions
  u16* Ytb  = qt;   // dead after attention
  u16* Ysb  = kt;
  u16* attB = vt;
  u16* Yfb  = qs;
  u16* h1   = wcat; // dead after gemm_qkv
  float* out = (float*)d_out;

  // 1. fused prep (zero accs + conversions + weight pack)
  k_prep<<<40776, 256, 0, stream>>>(src, x_bf, Wp_t, wptb, Wp_s, wpsb, W1, w1b, W2, w2b,
                                    Wq_t, Wk_t, Wv_t, Wq_s, Wk_s, Wv_s, wcat, accT);
  // 2. QKV projections (per joint; A staged once, 6 B-chunks)
  gemm_qkv<<<dim3(30,24), 256, 0, stream>>>(x_bf, wcat, qt, kt, vt, qs, ks, vs);
  // 3. both attentions in one launch
  attn_both<<<9984, 256, 0, stream>>>(qt, kt, vt, tab, qs, ks, vs, sab);
  // 4. output projections + residual + fused BN stats (256x384, 240 blocks, XCD-chunked)
  gemm_proj384<<<dim3(15,8,2), 512, 0, stream>>>(tab, wptb, bp_t, sab, wpsb, bp_s,
                                                 x_bf, Ytb, Ysb, accT, accS);
  // 5. BN coefs (t+s) + fused apply
  bn_coef2<<<24, 256, 0, stream>>>(accT, g_t, b_t, cT, accS, g_s, b_s, cS);
  bn_apply2<<<11520, 256, 0, stream>>>(Ytb, Ysb, cT, cS, attB);
  // 6. feed-forward
  gemm_relu<<<dim3(30,2), 256, 0, stream>>>(attB, w1b, 3072, 256, b1, h1);
  gemm_ff2<<<dim3(30,24), 256, 0, stream>>>(h1, w2b, b2, attB, Yfb, accF);
  // 7. final BN
  bn_coef<<<12, 256, 0, stream>>>(accF, g_f, b_f, cF);
  bn_out<<<11520, 256, 0, stream>>>(Yfb, cF, out);
}